// Round 3
// baseline (1323.599 us; speedup 1.0000x reference)
//
#include <hip/hip_runtime.h>
#include <math.h>

static constexpr int NN = 50000;     // nodes
static constexpr long NE = 800000;   // edges
static constexpr int FF = 64;        // features
static constexpr int EDIM = 16;      // edge attr dim
static constexpr int NLAYER = 2;
static constexpr float EPSBN = 1e-5f;
static constexpr int NTILE = 16;                 // nodes per block-iteration in node kernel
static constexpr int NTILES = NN / NTILE;        // 3125 (exact)

// ---- fold weights: Weff = We @ Wpre[64:128], beff = bpre + be@Wpre[64:128],
//      Wc = Wpost @ Wlin, cfold = bpost@Wlin + blin.  grid = NLAYER blocks ----
__global__ void fold_kernel(const float* __restrict__ We, const float* __restrict__ be,
                            const float* __restrict__ Wpre, const float* __restrict__ bpre,
                            const float* __restrict__ Wpost, const float* __restrict__ bpost,
                            const float* __restrict__ Wlin, const float* __restrict__ blin,
                            float* __restrict__ Weff, float* __restrict__ beff,
                            float* __restrict__ Wc, float* __restrict__ cfold) {
    int l = blockIdx.x;
    int t = threadIdx.x;
    const float* We_l    = We    + l * EDIM * FF;
    const float* Wpre_e  = Wpre  + l * 2 * FF * FF + FF * FF;  // rows 64..127
    const float* Wpost_l = Wpost + l * 7 * FF * FF;
    const float* Wlin_l  = Wlin  + l * FF * FF;

    __shared__ float slin[FF * FF];
    __shared__ float spre[FF * FF];
    for (int i = t; i < FF * FF; i += blockDim.x) { slin[i] = Wlin_l[i]; spre[i] = Wpre_e[i]; }
    __syncthreads();

    for (int i = t; i < EDIM * FF; i += blockDim.x) {
        int j = i >> 6, f = i & 63;
        float a = 0.f;
        for (int k = 0; k < FF; ++k) a += We_l[j * FF + k] * spre[k * FF + f];
        Weff[l * EDIM * FF + i] = a;
    }
    for (int i = t; i < FF; i += blockDim.x) {
        float a = bpre[l * FF + i];
        for (int k = 0; k < FF; ++k) a += be[l * FF + k] * spre[k * FF + i];
        beff[l * FF + i] = a;
    }
    for (int i = t; i < 7 * FF * FF; i += blockDim.x) {
        int r = i >> 6, f = i & 63;
        float a = 0.f;
        for (int k = 0; k < FF; ++k) a += Wpost_l[r * FF + k] * slin[k * FF + f];
        Wc[l * 7 * FF * FF + i] = a;
    }
    for (int i = t; i < FF; i += blockDim.x) {
        float a = blin[l * FF + i];
        for (int k = 0; k < FF; ++k) a += bpost[l * FF + k] * slin[k * FF + i];
        cfold[l * FF + i] = a;
    }
}

// ================= CSR build phase (once per call; graph is layer-invariant) ==========

__global__ void build_zero(int* __restrict__ rowcnt, int* __restrict__ fill,
                           int* __restrict__ bc, float* __restrict__ avglog) {
    long i = (long)blockIdx.x * 256 + threadIdx.x;
    long stride = (long)gridDim.x * 256;
    for (long j = i; j < NN; j += stride) { rowcnt[j] = 0; fill[j] = 0; bc[j] = 0; }
    if (i == 0) avglog[0] = 0.f;
}

__global__ void hist_dst(const int* __restrict__ ei, int* __restrict__ rowcnt) {
    long e = (long)blockIdx.x * 256 + threadIdx.x;
    if (e < NE) atomicAdd(&rowcnt[ei[NE + e]], 1);
}

// exclusive scan of rowcnt[NN] -> rowptr[NN+1], single block of 1024 threads
__global__ void scan_kernel(const int* __restrict__ rowcnt, int* __restrict__ rowptr) {
    __shared__ int part[1024];
    int t = threadIdx.x;
    const int CH = 49;  // 1024*49 >= 50000
    int lo = t * CH, hi = lo + CH; if (hi > NN) hi = NN; if (lo > NN) lo = NN;
    int s = 0;
    for (int i = lo; i < hi; ++i) s += rowcnt[i];
    part[t] = s;
    __syncthreads();
    for (int o = 1; o < 1024; o <<= 1) {
        int v = (t >= o) ? part[t - o] : 0;
        __syncthreads();
        part[t] += v;
        __syncthreads();
    }
    int ex = (t == 0) ? 0 : part[t - 1];
    for (int i = lo; i < hi; ++i) { rowptr[i] = ex; ex += rowcnt[i]; }
    if (t == 1023) rowptr[NN] = part[1023];
}

// scatter edges into CSR order; pre-gather src and attr into permuted arrays
__global__ void scatter_kernel(const int* __restrict__ ei, const float* __restrict__ attr,
                               const int* __restrict__ rowptr, int* __restrict__ fill,
                               int* __restrict__ srcp, float* __restrict__ attrp) {
    long e = (long)blockIdx.x * 256 + threadIdx.x;
    if (e >= NE) return;
    int d = ei[NE + e];
    int p = rowptr[d] + atomicAdd(&fill[d], 1);
    srcp[p] = ei[e];
    const float4* a = (const float4*)(attr + e * EDIM);
    float4* o = (float4*)(attrp + (long)p * EDIM);
    o[0] = a[0]; o[1] = a[1]; o[2] = a[2]; o[3] = a[3];
}

__global__ void degbc(const int* __restrict__ rowcnt, int* __restrict__ bc) {
    long n = (long)blockIdx.x * 256 + threadIdx.x;
    if (n < NN) {
        int d = rowcnt[n];
        if (d >= NN) d = NN - 1;
        atomicAdd(&bc[d], 1);
    }
}

__global__ void avglog_kernel(const int* __restrict__ bc, float* __restrict__ total) {
    float s = 0.f;
    for (long i = (long)blockIdx.x * 256 + threadIdx.x; i < NN; i += (long)gridDim.x * 256)
        s += logf((float)bc[i] + 1.f);
    for (int o = 32; o; o >>= 1) s += __shfl_down(s, o, 64);
    __shared__ float wsum[4];
    int lane = threadIdx.x & 63, wid = threadIdx.x >> 6;
    if (lane == 0) wsum[wid] = s;
    __syncthreads();
    if (threadIdx.x == 0) atomicAdd(total, wsum[0] + wsum[1] + wsum[2] + wsum[3]);
}

__global__ void amp_kernel(const int* __restrict__ cnt, const float* __restrict__ total,
                           float* __restrict__ amp) {
    long n = (long)blockIdx.x * 256 + threadIdx.x;
    if (n < NN) {
        float avg = total[0] / (float)NN;
        float sc = fmaxf((float)cnt[n], 1.f);
        amp[n] = logf(sc + 1.f) / avg;
    }
}

// ================= per-layer kernels ==========

// xp = x @ Wpre[0:64]; wave per node, lane = out feature, weights in VGPRs
__global__ __launch_bounds__(256) void xp2_kernel(const float* __restrict__ x,
                                                  const float* __restrict__ Wpre_l,
                                                  float* __restrict__ xp) {
    int t = threadIdx.x;
    int lane = t & 63, wid = t >> 6;
    float wr[FF];
#pragma unroll
    for (int k = 0; k < FF; ++k) wr[k] = Wpre_l[k * FF + lane];
    for (long n = (long)blockIdx.x * 4 + wid; n < NN; n += (long)gridDim.x * 4) {
        const float4* v4 = (const float4*)(x + n * FF);
        float acc = 0.f;
#pragma unroll
        for (int q = 0; q < 16; ++q) {
            float4 a = v4[q];
            acc = fmaf(a.x, wr[4 * q + 0], acc);
            acc = fmaf(a.y, wr[4 * q + 1], acc);
            acc = fmaf(a.z, wr[4 * q + 2], acc);
            acc = fmaf(a.w, wr[4 * q + 3], acc);
        }
        xp[n * FF + lane] = acc;
    }
}

// CSR aggregation: wave per dst node; h = xp[src] + attr@Weff + beff; register reduce.
// Software-pipelined: next edge's xp row is prefetched while current h is computed.
__global__ __launch_bounds__(256) void agg_kernel(
    const int* __restrict__ rowptr, const int* __restrict__ srcp,
    const float* __restrict__ attrp, const float* __restrict__ Weff_l,
    const float* __restrict__ beff_l, const float* __restrict__ xp,
    float* __restrict__ meanb, float* __restrict__ mnb, float* __restrict__ mxb) {
    int t = threadIdx.x;
    int lane = t & 63, wid = t >> 6;
    float wr[EDIM];
#pragma unroll
    for (int k = 0; k < EDIM; ++k) wr[k] = Weff_l[k * FF + lane];
    float bf = beff_l[lane];
    const float INF = __builtin_huge_valf();
    for (long n = (long)blockIdx.x * 4 + wid; n < NN; n += (long)gridDim.x * 4) {
        int r0 = rowptr[n], r1 = rowptr[n + 1];
        float sm = 0.f, mn = INF, mx = -INF;
        float xv_next = 0.f;
        if (r0 < r1) xv_next = xp[(long)srcp[r0] * FF + lane];
        for (int e = r0; e < r1; ++e) {
            float xv = xv_next;
            if (e + 1 < r1) xv_next = xp[(long)srcp[e + 1] * FF + lane];
            float h = xv + bf;
            const float4* a4 = (const float4*)(attrp + (long)e * EDIM);
            float4 a0 = a4[0], a1 = a4[1], a2 = a4[2], a3 = a4[3];
            h = fmaf(a0.x, wr[0], h);  h = fmaf(a0.y, wr[1], h);
            h = fmaf(a0.z, wr[2], h);  h = fmaf(a0.w, wr[3], h);
            h = fmaf(a1.x, wr[4], h);  h = fmaf(a1.y, wr[5], h);
            h = fmaf(a1.z, wr[6], h);  h = fmaf(a1.w, wr[7], h);
            h = fmaf(a2.x, wr[8], h);  h = fmaf(a2.y, wr[9], h);
            h = fmaf(a2.z, wr[10], h); h = fmaf(a2.w, wr[11], h);
            h = fmaf(a3.x, wr[12], h); h = fmaf(a3.y, wr[13], h);
            h = fmaf(a3.z, wr[14], h); h = fmaf(a3.w, wr[15], h);
            sm += h;
            mn = fminf(mn, h);
            mx = fmaxf(mx, h);
        }
        int deg = r1 - r0;
        if (deg == 0) { mn = 0.f; mx = 0.f; }
        float me = sm / fmaxf((float)deg, 1.f);
        long o = n * FF + lane;
        meanb[o] = me; mnb[o] = mn; mxb[o] = mx;
    }
}

__global__ void initbn(float* __restrict__ bnsum, float* __restrict__ bnsum2) {
    int t = threadIdx.x;
    if (t < FF) { bnsum[t] = 0.f; bnsum2[t] = 0.f; }
}

// node GEMM: out = cat(x,mean,mn,mx, amp*(mean,mn,mx)) @ Wc + cfold; BN partials.
// 7 waves/block, wave w owns K-segment [64w,64w+64) with its Wc slice in VGPRs.
// NTILE=16 nodes per block-iteration: 16 independent accumulators per wave hide
// uniform-load latency; barriers amortized 16x; reduce spread over all 448 threads.
__global__ __launch_bounds__(448) void node3_kernel(
    const float* __restrict__ x, const float* __restrict__ meanb,
    const float* __restrict__ mnb, const float* __restrict__ mxb,
    const float* __restrict__ ampb, const float* __restrict__ Wc_l,
    const float* __restrict__ cfold_l, float* __restrict__ out_pre,
    float* __restrict__ bnsum, float* __restrict__ bnsum2) {
    int t = threadIdx.x;
    int lane = t & 63, w = t >> 6;  // w in 0..6
    float wr[FF];
#pragma unroll
    for (int k = 0; k < FF; ++k) wr[k] = Wc_l[(w * FF + k) * FF + lane];
    const float* srcarr = (w == 0) ? x
                        : (w == 1 || w == 4) ? meanb
                        : (w == 2 || w == 5) ? mnb : mxb;
    bool scaled = (w >= 4);
    float cf = cfold_l[lane];  // lane == output feature in reduce phase too
    __shared__ float part[7][NTILE][FF];
    float bs = 0.f, bs2 = 0.f;

    for (int tile = blockIdx.x; tile < NTILES; tile += gridDim.x) {
        long n0 = (long)tile * NTILE;
        const float4* b4 = (const float4*)(srcarr + n0 * FF);
        float acc[NTILE];
#pragma unroll
        for (int j = 0; j < NTILE; ++j) acc[j] = 0.f;
#pragma unroll
        for (int j = 0; j < NTILE; ++j) {
#pragma unroll
            for (int q = 0; q < 16; ++q) {
                float4 a = b4[j * 16 + q];
                acc[j] = fmaf(a.x, wr[4 * q + 0], acc[j]);
                acc[j] = fmaf(a.y, wr[4 * q + 1], acc[j]);
                acc[j] = fmaf(a.z, wr[4 * q + 2], acc[j]);
                acc[j] = fmaf(a.w, wr[4 * q + 3], acc[j]);
            }
        }
        if (scaled) {
#pragma unroll
            for (int j = 0; j < NTILE; ++j) acc[j] *= ampb[n0 + j];
        }
        __syncthreads();  // part[] free (prev iteration's reads done)
#pragma unroll
        for (int j = 0; j < NTILE; ++j) part[w][j][lane] = acc[j];
        __syncthreads();
        // reduce: 1024 outputs over 448 threads, 3 rounds; f = t&63 each round
#pragma unroll
        for (int r = 0; r < 3; ++r) {
            int o = t + r * 448;
            if (o < NTILE * FF) {
                int j = o >> 6, f = o & 63;
                float s = cf + part[0][j][f] + part[1][j][f] + part[2][j][f]
                        + part[3][j][f] + part[4][j][f] + part[5][j][f] + part[6][j][f];
                out_pre[(n0 + j) * FF + f] = s;
                bs += s;
                bs2 += s * s;
            }
        }
    }
    atomicAdd(&bnsum[lane], bs);
    atomicAdd(&bnsum2[lane], bs2);
}

__global__ void bn_final(const float* __restrict__ bnsum, const float* __restrict__ bnsum2,
                         const float* __restrict__ gamma_l, const float* __restrict__ beta_l,
                         float* __restrict__ sc_sh) {
    int f = threadIdx.x;
    if (f < FF) {
        float mu = bnsum[f] / (float)NN;
        float var = bnsum2[f] / (float)NN - mu * mu;
        var = fmaxf(var, 0.f);
        float s = gamma_l[f] * rsqrtf(var + EPSBN);
        sc_sh[f] = s;
        sc_sh[FF + f] = beta_l[f] - mu * s;
    }
}

__global__ void bn_apply(const float* __restrict__ out_pre, const float* __restrict__ sc_sh,
                         float* __restrict__ xout) {
    long i = (long)blockIdx.x * 256 + threadIdx.x;
    long stride = (long)gridDim.x * 256;
    for (long j = i; j < (long)NN * FF; j += stride) {
        int f = (int)(j & 63);
        float y = fmaf(out_pre[j], sc_sh[f], sc_sh[FF + f]);
        xout[j] = fmaxf(y, 0.f);
    }
}

extern "C" void kernel_launch(void* const* d_in, const int* in_sizes, int n_in,
                              void* d_out, int out_size, void* d_ws, size_t ws_size,
                              hipStream_t stream) {
    const float* x0    = (const float*)d_in[0];
    const int*   ei    = (const int*)d_in[1];
    const float* attr  = (const float*)d_in[2];
    const float* We    = (const float*)d_in[3];
    const float* be    = (const float*)d_in[4];
    const float* Wpre  = (const float*)d_in[5];
    const float* bpre  = (const float*)d_in[6];
    const float* Wpost = (const float*)d_in[7];
    const float* bpost = (const float*)d_in[8];
    const float* Wlin  = (const float*)d_in[9];
    const float* blin  = (const float*)d_in[10];
    const float* gamma = (const float*)d_in[11];
    const float* beta  = (const float*)d_in[12];
    float* out = (float*)d_out;

    char* ws = (char*)d_ws;
    size_t off = 0;
    auto carve = [&](size_t bytes) -> void* {
        void* p = ws + off;
        off += (bytes + 255) & ~(size_t)255;
        return p;
    };
    const size_t NFb = (size_t)NN * FF * 4;
    float*    Weff   = (float*)carve(2 * EDIM * FF * 4);
    float*    beff   = (float*)carve(2 * FF * 4);
    float*    Wc     = (float*)carve(2 * 7 * FF * FF * 4);
    float*    cfold  = (float*)carve(2 * FF * 4);
    float*    attrp  = (float*)carve((size_t)NE * EDIM * 4);  // 51.2 MB
    int*      srcp   = (int*)carve(NE * 4);
    int*      rowptr = (int*)carve((NN + 1) * 4);
    int*      rowcnt = (int*)carve(NN * 4);
    int*      fill   = (int*)carve(NN * 4);
    int*      bc     = (int*)carve(NN * 4);
    float*    amp    = (float*)carve(NN * 4);
    float*    xp     = (float*)carve(NFb);   // aliased as out_pre after agg
    float*    meanb  = (float*)carve(NFb);
    float*    mnb    = (float*)carve(NFb);
    float*    mxb    = (float*)carve(NFb);
    float*    xbuf   = (float*)carve(NFb);
    float*    bnsum  = (float*)carve(FF * 4);
    float*    bnsum2 = (float*)carve(FF * 4);
    float*    avglog = (float*)carve(4);
    float*    sc_sh  = (float*)carve(2 * FF * 4);
    float*    out_pre = xp;  // xp dead after agg_kernel each layer

    const int EB = (int)((NE + 255) / 256);

    // one-time build
    build_zero<<<196, 256, 0, stream>>>(rowcnt, fill, bc, avglog);
    hist_dst<<<EB, 256, 0, stream>>>(ei, rowcnt);
    scan_kernel<<<1, 1024, 0, stream>>>(rowcnt, rowptr);
    scatter_kernel<<<EB, 256, 0, stream>>>(ei, attr, rowptr, fill, srcp, attrp);
    degbc<<<196, 256, 0, stream>>>(rowcnt, bc);
    avglog_kernel<<<128, 256, 0, stream>>>(bc, avglog);
    amp_kernel<<<196, 256, 0, stream>>>(rowcnt, avglog, amp);
    fold_kernel<<<NLAYER, 256, 0, stream>>>(We, be, Wpre, bpre, Wpost, bpost, Wlin, blin,
                                            Weff, beff, Wc, cfold);

    for (int l = 0; l < NLAYER; ++l) {
        const float* xin = (l == 0) ? x0 : xbuf;
        float* xout = (l == NLAYER - 1) ? out : xbuf;

        xp2_kernel<<<12500, 256, 0, stream>>>(xin, Wpre + (size_t)l * 2 * FF * FF, xp);
        agg_kernel<<<12500, 256, 0, stream>>>(rowptr, srcp, attrp,
                                              Weff + l * EDIM * FF, beff + l * FF,
                                              xp, meanb, mnb, mxb);
        initbn<<<1, 64, 0, stream>>>(bnsum, bnsum2);
        node3_kernel<<<512, 448, 0, stream>>>(xin, meanb, mnb, mxb, amp,
                                              Wc + (size_t)l * 7 * FF * FF, cfold + l * FF,
                                              out_pre, bnsum, bnsum2);
        bn_final<<<1, 64, 0, stream>>>(bnsum, bnsum2, gamma + l * FF, beta + l * FF, sc_sh);
        bn_apply<<<4096, 256, 0, stream>>>(out_pre, sc_sh, xout);
    }
}

// Round 4
// 801.949 us; speedup vs baseline: 1.6505x; 1.6505x over previous
//
#include <hip/hip_runtime.h>
#include <math.h>

static constexpr int NN = 50000;     // nodes
static constexpr long NE = 800000;   // edges
static constexpr int FF = 64;        // features
static constexpr int EDIM = 16;      // edge attr dim
static constexpr int NLAYER = 2;
static constexpr float EPSBN = 1e-5f;
static constexpr int NGRP = NN / 16;         // 3125 node groups of 16
static constexpr long ECH = NE / 2;          // edge chunk (400000)

typedef __attribute__((ext_vector_type(8))) short short8v;
typedef __attribute__((ext_vector_type(4))) float f32x4;

#define MFMA16(a, b, c) __builtin_amdgcn_mfma_f32_16x16x32_bf16(a, b, c, 0, 0, 0)

__device__ __forceinline__ short f2bf(float f) {
    unsigned u = __float_as_uint(f);
    unsigned r = u + 0x7FFFu + ((u >> 16) & 1u);   // RNE
    return (short)(r >> 16);
}
__device__ __forceinline__ float bf2f(unsigned short h) {
    return __uint_as_float(((unsigned)h) << 16);
}
__device__ __forceinline__ short8v pack8(const float* p) {
    const float4* q = (const float4*)p;
    float4 a = q[0], b = q[1];
    short8v v;
    v[0] = f2bf(a.x); v[1] = f2bf(a.y); v[2] = f2bf(a.z); v[3] = f2bf(a.w);
    v[4] = f2bf(b.x); v[5] = f2bf(b.y); v[6] = f2bf(b.z); v[7] = f2bf(b.w);
    return v;
}
__device__ __forceinline__ short8v pack8f(float f0, float f1, float f2, float f3,
                                          float f4, float f5, float f6, float f7) {
    short8v v;
    v[0] = f2bf(f0); v[1] = f2bf(f1); v[2] = f2bf(f2); v[3] = f2bf(f3);
    v[4] = f2bf(f4); v[5] = f2bf(f5); v[6] = f2bf(f6); v[7] = f2bf(f7);
    return v;
}

// ---- fold weights: Weff = We @ Wpre[64:128], beff = bpre + be@Wpre[64:128],
//      Wc = Wpost @ Wlin, cfold = bpost@Wlin + blin ----
__global__ void fold_kernel(const float* __restrict__ We, const float* __restrict__ be,
                            const float* __restrict__ Wpre, const float* __restrict__ bpre,
                            const float* __restrict__ Wpost, const float* __restrict__ bpost,
                            const float* __restrict__ Wlin, const float* __restrict__ blin,
                            float* __restrict__ Weff, float* __restrict__ beff,
                            float* __restrict__ Wc, float* __restrict__ cfold) {
    int l = blockIdx.x;
    int t = threadIdx.x;
    const float* We_l    = We    + l * EDIM * FF;
    const float* Wpre_e  = Wpre  + l * 2 * FF * FF + FF * FF;  // rows 64..127
    const float* Wpost_l = Wpost + l * 7 * FF * FF;
    const float* Wlin_l  = Wlin  + l * FF * FF;

    __shared__ float slin[FF * FF];
    __shared__ float spre[FF * FF];
    for (int i = t; i < FF * FF; i += blockDim.x) { slin[i] = Wlin_l[i]; spre[i] = Wpre_e[i]; }
    __syncthreads();

    for (int i = t; i < EDIM * FF; i += blockDim.x) {
        int j = i >> 6, f = i & 63;
        float a = 0.f;
        for (int k = 0; k < FF; ++k) a += We_l[j * FF + k] * spre[k * FF + f];
        Weff[l * EDIM * FF + i] = a;
    }
    for (int i = t; i < FF; i += blockDim.x) {
        float a = bpre[l * FF + i];
        for (int k = 0; k < FF; ++k) a += be[l * FF + k] * spre[k * FF + i];
        beff[l * FF + i] = a;
    }
    for (int i = t; i < 7 * FF * FF; i += blockDim.x) {
        int r = i >> 6, f = i & 63;
        float a = 0.f;
        for (int k = 0; k < FF; ++k) a += Wpost_l[r * FF + k] * slin[k * FF + f];
        Wc[l * 7 * FF * FF + i] = a;
    }
    for (int i = t; i < FF; i += blockDim.x) {
        float a = blin[l * FF + i];
        for (int k = 0; k < FF; ++k) a += bpost[l * FF + k] * slin[k * FF + i];
        cfold[l * FF + i] = a;
    }
}

// ---- pack B [K x 64] f32 -> fragment-major bf16: frag[(kc*4+nt)*64+lane][j],
//      element j: k = kc*32 + (lane>>4)*8 + j, n = nt*16 + (lane&15) ----
__global__ void fragify(const float* __restrict__ src, short* __restrict__ dst,
                        int KC, int Kreal) {
    int idx = blockIdx.x * 256 + threadIdx.x;
    if (idx >= KC * 256) return;
    int lane = idx & 63, nt = (idx >> 6) & 3, kc = idx >> 8;
    int m = lane & 15, kh = lane >> 4;
    short8v v;
#pragma unroll
    for (int j = 0; j < 8; ++j) {
        int k = kc * 32 + kh * 8 + j;
        float val = (k < Kreal) ? src[k * FF + nt * 16 + m] : 0.f;
        v[j] = f2bf(val);
    }
    ((short8v*)dst)[idx] = v;
}

// ================= CSR build phase ==========

__global__ void build_zero(int* __restrict__ rowcnt, int* __restrict__ fill,
                           int* __restrict__ bc, float* __restrict__ avglog) {
    long i = (long)blockIdx.x * 256 + threadIdx.x;
    long stride = (long)gridDim.x * 256;
    for (long j = i; j < NN; j += stride) { rowcnt[j] = 0; fill[j] = 0; bc[j] = 0; }
    if (i == 0) avglog[0] = 0.f;
}

__global__ void hist_dst(const int* __restrict__ ei, int* __restrict__ rowcnt) {
    long e = (long)blockIdx.x * 256 + threadIdx.x;
    if (e < NE) atomicAdd(&rowcnt[ei[NE + e]], 1);
}

__global__ void scan_kernel(const int* __restrict__ rowcnt, int* __restrict__ rowptr) {
    __shared__ int part[1024];
    int t = threadIdx.x;
    const int CH = 49;
    int lo = t * CH, hi = lo + CH; if (hi > NN) hi = NN; if (lo > NN) lo = NN;
    int s = 0;
    for (int i = lo; i < hi; ++i) s += rowcnt[i];
    part[t] = s;
    __syncthreads();
    for (int o = 1; o < 1024; o <<= 1) {
        int v = (t >= o) ? part[t - o] : 0;
        __syncthreads();
        part[t] += v;
        __syncthreads();
    }
    int ex = (t == 0) ? 0 : part[t - 1];
    for (int i = lo; i < hi; ++i) { rowptr[i] = ex; ex += rowcnt[i]; }
    if (t == 1023) rowptr[NN] = part[1023];
}

// CSR order: srcp[p] = src node, perm[p] = original edge id (for attr gather)
__global__ void scatter2(const int* __restrict__ ei, const int* __restrict__ rowptr,
                         int* __restrict__ fill, int* __restrict__ srcp,
                         int* __restrict__ perm) {
    long e = (long)blockIdx.x * 256 + threadIdx.x;
    if (e >= NE) return;
    int d = ei[NE + e];
    int p = rowptr[d] + atomicAdd(&fill[d], 1);
    srcp[p] = ei[e];
    perm[p] = (int)e;
}

__global__ void degbc(const int* __restrict__ rowcnt, int* __restrict__ bc) {
    long n = (long)blockIdx.x * 256 + threadIdx.x;
    if (n < NN) {
        int d = rowcnt[n];
        if (d >= NN) d = NN - 1;
        atomicAdd(&bc[d], 1);
    }
}

__global__ void avglog_kernel(const int* __restrict__ bc, float* __restrict__ total) {
    float s = 0.f;
    for (long i = (long)blockIdx.x * 256 + threadIdx.x; i < NN; i += (long)gridDim.x * 256)
        s += logf((float)bc[i] + 1.f);
    for (int o = 32; o; o >>= 1) s += __shfl_down(s, o, 64);
    __shared__ float wsum[4];
    int lane = threadIdx.x & 63, wid = threadIdx.x >> 6;
    if (lane == 0) wsum[wid] = s;
    __syncthreads();
    if (threadIdx.x == 0) atomicAdd(total, wsum[0] + wsum[1] + wsum[2] + wsum[3]);
}

__global__ void amp_kernel(const int* __restrict__ cnt, const float* __restrict__ total,
                           float* __restrict__ amp) {
    long n = (long)blockIdx.x * 256 + threadIdx.x;
    if (n < NN) {
        float avg = total[0] / (float)NN;
        float sc = fmaxf((float)cnt[n], 1.f);
        amp[n] = logf(sc + 1.f) / avg;
    }
}

// ================= per-layer kernels ==========

__global__ void init_layer(float* __restrict__ sumb, float* __restrict__ mnb,
                           float* __restrict__ mxb, float* __restrict__ bnsum,
                           float* __restrict__ bnsum2) {
    long i = (long)blockIdx.x * 256 + threadIdx.x;
    long stride = (long)gridDim.x * 256;
    const float INF = __builtin_huge_valf();
    for (long j = i; j < (long)NN * FF; j += stride) {
        sumb[j] = 0.f; mnb[j] = INF; mxb[j] = -INF;
    }
    if (i < FF) { bnsum[i] = 0.f; bnsum2[i] = 0.f; }
}

// xp = x @ Wpre[0:64] -> bf16, via MFMA. wave per 16-node group.
__global__ __launch_bounds__(256) void xp_mfma(const float* __restrict__ xin,
                                               const short* __restrict__ WF,
                                               short* __restrict__ xpb) {
    int t = threadIdx.x;
    int g = blockIdx.x * 4 + (t >> 6);
    if (g >= NGRP) return;
    int lane = t & 63, m = lane & 15, kh = lane >> 4;
    const float* xr = xin + (long)(g * 16 + m) * FF;
    short8v a0 = pack8(xr + kh * 8);
    short8v a1 = pack8(xr + 32 + kh * 8);
    const short8v* BF = (const short8v*)WF;
    f32x4 acc[4];
#pragma unroll
    for (int nt = 0; nt < 4; ++nt) {
        f32x4 z = {0.f, 0.f, 0.f, 0.f};
        z = MFMA16(a0, BF[(0 * 4 + nt) * 64 + lane], z);
        z = MFMA16(a1, BF[(1 * 4 + nt) * 64 + lane], z);
        acc[nt] = z;
    }
#pragma unroll
    for (int nt = 0; nt < 4; ++nt)
#pragma unroll
        for (int r = 0; r < 4; ++r) {
            long node = g * 16 + kh * 4 + r;
            xpb[node * FF + nt * 16 + m] = f2bf(acc[nt][r]);
        }
}

// ep = attr[perm] @ Weff + beff -> bf16 (CSR-ordered, chunked). wave per 16 edges.
__global__ __launch_bounds__(256) void ep_mfma(const float* __restrict__ attr,
                                               const int* __restrict__ perm,
                                               const short* __restrict__ WF,
                                               const float* __restrict__ beff_l,
                                               short* __restrict__ epc, long elo) {
    int t = threadIdx.x;
    int g = blockIdx.x * 4 + (t >> 6);   // 0..ECH/16-1 (exact)
    int lane = t & 63, m = lane & 15, kh = lane >> 4;
    long p0 = elo + (long)g * 16;
    int orig = perm[p0 + m];
    short8v a;
    if (kh < 2) {
        a = pack8(attr + (long)orig * EDIM + kh * 8);
    } else {
#pragma unroll
        for (int j = 0; j < 8; ++j) a[j] = 0;
    }
    const short8v* BF = (const short8v*)WF;
    float bfv[4];
#pragma unroll
    for (int nt = 0; nt < 4; ++nt) bfv[nt] = beff_l[nt * 16 + m];
    f32x4 acc[4];
#pragma unroll
    for (int nt = 0; nt < 4; ++nt) {
        f32x4 z = {0.f, 0.f, 0.f, 0.f};
        acc[nt] = MFMA16(a, BF[nt * 64 + lane], z);
    }
#pragma unroll
    for (int nt = 0; nt < 4; ++nt)
#pragma unroll
        for (int r = 0; r < 4; ++r) {
            long rel = (long)g * 16 + kh * 4 + r;
            epc[rel * FF + nt * 16 + m] = f2bf(acc[nt][r] + bfv[nt]);
        }
}

// CSR aggregation over edge chunk [elo,ehi): h = xp[src] + ep; merge into f32 state.
__global__ __launch_bounds__(256) void agg_merge(
    const int* __restrict__ rowptr, const int* __restrict__ srcp,
    const short* __restrict__ xpb, const short* __restrict__ epc,
    long elo, long ehi,
    float* __restrict__ sumb, float* __restrict__ mnb, float* __restrict__ mxb) {
    int t = threadIdx.x;
    int n = blockIdx.x * 4 + (t >> 6);
    if (n >= NN) return;
    int lane = t & 63;
    long r0 = rowptr[n], r1 = rowptr[n + 1];
    long lo = r0 > elo ? r0 : elo;
    long hi = r1 < ehi ? r1 : ehi;
    if (lo >= hi) return;
    const unsigned short* xu = (const unsigned short*)xpb;
    const unsigned short* eu = (const unsigned short*)epc;
    const float INF = __builtin_huge_valf();
    float sm = 0.f, mn = INF, mx = -INF;
    int s = srcp[lo];
    float xv = bf2f(xu[(long)s * FF + lane]);
    float ev = bf2f(eu[(lo - elo) * FF + lane]);
    for (long e = lo; e < hi; ++e) {
        float h = xv + ev;
        if (e + 1 < hi) {
            int s2 = srcp[e + 1];
            xv = bf2f(xu[(long)s2 * FF + lane]);
            ev = bf2f(eu[(e + 1 - elo) * FF + lane]);
        }
        sm += h;
        mn = fminf(mn, h);
        mx = fmaxf(mx, h);
    }
    long o = (long)n * FF + lane;
    sumb[o] += sm;
    mnb[o] = fminf(mnb[o], mn);
    mxb[o] = fmaxf(mxb[o], mx);
}

// node GEMM via MFMA: out = [x|mean|mn|mx|amp*(mean,mn,mx)] @ Wc + cfold; BN partials.
__global__ __launch_bounds__(256) void node_mfma(
    const float* __restrict__ xin, const float* __restrict__ sumb,
    const float* __restrict__ mnb, const float* __restrict__ mxb,
    const int* __restrict__ rowcnt, const float* __restrict__ amp,
    const short* __restrict__ WF, const float* __restrict__ cfold_l,
    float* __restrict__ out_pre, float* __restrict__ bnsum, float* __restrict__ bnsum2) {
    __shared__ float sS[FF], sQ[FF];
    int t = threadIdx.x;
    if (t < FF) { sS[t] = 0.f; sQ[t] = 0.f; }
    __syncthreads();
    int g = blockIdx.x * 4 + (t >> 6);
    bool act = (g < NGRP);
    int lane = t & 63, m = lane & 15, kh = lane >> 4;
    if (act) {
        long n = g * 16 + m;
        int deg = rowcnt[n];
        float inv = 1.f / fmaxf((float)deg, 1.f);
        bool has = (deg > 0);
        float av = amp[n];
        const float* xr = xin + n * FF;
        float vme[16], vmn[16], vmx[16];
        {
            const float4* s4a = (const float4*)(sumb + n * FF + kh * 8);
            const float4* s4b = (const float4*)(sumb + n * FF + 32 + kh * 8);
            float4 a = s4a[0], b = s4a[1], c = s4b[0], d = s4b[1];
            vme[0]=a.x*inv; vme[1]=a.y*inv; vme[2]=a.z*inv; vme[3]=a.w*inv;
            vme[4]=b.x*inv; vme[5]=b.y*inv; vme[6]=b.z*inv; vme[7]=b.w*inv;
            vme[8]=c.x*inv; vme[9]=c.y*inv; vme[10]=c.z*inv; vme[11]=c.w*inv;
            vme[12]=d.x*inv; vme[13]=d.y*inv; vme[14]=d.z*inv; vme[15]=d.w*inv;
        }
        {
            const float4* s4a = (const float4*)(mnb + n * FF + kh * 8);
            const float4* s4b = (const float4*)(mnb + n * FF + 32 + kh * 8);
            float4 a = s4a[0], b = s4a[1], c = s4b[0], d = s4b[1];
            vmn[0]=has?a.x:0.f; vmn[1]=has?a.y:0.f; vmn[2]=has?a.z:0.f; vmn[3]=has?a.w:0.f;
            vmn[4]=has?b.x:0.f; vmn[5]=has?b.y:0.f; vmn[6]=has?b.z:0.f; vmn[7]=has?b.w:0.f;
            vmn[8]=has?c.x:0.f; vmn[9]=has?c.y:0.f; vmn[10]=has?c.z:0.f; vmn[11]=has?c.w:0.f;
            vmn[12]=has?d.x:0.f; vmn[13]=has?d.y:0.f; vmn[14]=has?d.z:0.f; vmn[15]=has?d.w:0.f;
        }
        {
            const float4* s4a = (const float4*)(mxb + n * FF + kh * 8);
            const float4* s4b = (const float4*)(mxb + n * FF + 32 + kh * 8);
            float4 a = s4a[0], b = s4a[1], c = s4b[0], d = s4b[1];
            vmx[0]=has?a.x:0.f; vmx[1]=has?a.y:0.f; vmx[2]=has?a.z:0.f; vmx[3]=has?a.w:0.f;
            vmx[4]=has?b.x:0.f; vmx[5]=has?b.y:0.f; vmx[6]=has?b.z:0.f; vmx[7]=has?b.w:0.f;
            vmx[8]=has?c.x:0.f; vmx[9]=has?c.y:0.f; vmx[10]=has?c.z:0.f; vmx[11]=has?c.w:0.f;
            vmx[12]=has?d.x:0.f; vmx[13]=has?d.y:0.f; vmx[14]=has?d.z:0.f; vmx[15]=has?d.w:0.f;
        }
        const short8v* BF = (const short8v*)WF;
        f32x4 acc[4];
#pragma unroll
        for (int nt = 0; nt < 4; ++nt) { f32x4 z = {0.f,0.f,0.f,0.f}; acc[nt] = z; }
#define DO_KC(kc, afrag) { short8v aa = (afrag); \
        _Pragma("unroll") for (int nt = 0; nt < 4; ++nt) \
            acc[nt] = MFMA16(aa, BF[((kc) * 4 + nt) * 64 + lane], acc[nt]); }
        DO_KC(0, pack8(xr + kh * 8))
        DO_KC(1, pack8(xr + 32 + kh * 8))
        DO_KC(2, pack8f(vme[0],vme[1],vme[2],vme[3],vme[4],vme[5],vme[6],vme[7]))
        DO_KC(3, pack8f(vme[8],vme[9],vme[10],vme[11],vme[12],vme[13],vme[14],vme[15]))
        DO_KC(4, pack8f(vmn[0],vmn[1],vmn[2],vmn[3],vmn[4],vmn[5],vmn[6],vmn[7]))
        DO_KC(5, pack8f(vmn[8],vmn[9],vmn[10],vmn[11],vmn[12],vmn[13],vmn[14],vmn[15]))
        DO_KC(6, pack8f(vmx[0],vmx[1],vmx[2],vmx[3],vmx[4],vmx[5],vmx[6],vmx[7]))
        DO_KC(7, pack8f(vmx[8],vmx[9],vmx[10],vmx[11],vmx[12],vmx[13],vmx[14],vmx[15]))
        DO_KC(8, pack8f(vme[0]*av,vme[1]*av,vme[2]*av,vme[3]*av,vme[4]*av,vme[5]*av,vme[6]*av,vme[7]*av))
        DO_KC(9, pack8f(vme[8]*av,vme[9]*av,vme[10]*av,vme[11]*av,vme[12]*av,vme[13]*av,vme[14]*av,vme[15]*av))
        DO_KC(10, pack8f(vmn[0]*av,vmn[1]*av,vmn[2]*av,vmn[3]*av,vmn[4]*av,vmn[5]*av,vmn[6]*av,vmn[7]*av))
        DO_KC(11, pack8f(vmn[8]*av,vmn[9]*av,vmn[10]*av,vmn[11]*av,vmn[12]*av,vmn[13]*av,vmn[14]*av,vmn[15]*av))
        DO_KC(12, pack8f(vmx[0]*av,vmx[1]*av,vmx[2]*av,vmx[3]*av,vmx[4]*av,vmx[5]*av,vmx[6]*av,vmx[7]*av))
        DO_KC(13, pack8f(vmx[8]*av,vmx[9]*av,vmx[10]*av,vmx[11]*av,vmx[12]*av,vmx[13]*av,vmx[14]*av,vmx[15]*av))
#undef DO_KC
        float cfv[4];
#pragma unroll
        for (int nt = 0; nt < 4; ++nt) cfv[nt] = cfold_l[nt * 16 + m];
#pragma unroll
        for (int nt = 0; nt < 4; ++nt) {
            float ps = 0.f, pq = 0.f;
#pragma unroll
            for (int r = 0; r < 4; ++r) {
                float v = acc[nt][r] + cfv[nt];
                out_pre[(long)(g * 16 + kh * 4 + r) * FF + nt * 16 + m] = v;
                ps += v;
                pq += v * v;
            }
            atomicAdd(&sS[nt * 16 + m], ps);
            atomicAdd(&sQ[nt * 16 + m], pq);
        }
    }
    __syncthreads();
    if (t < FF) {
        atomicAdd(&bnsum[t], sS[t]);
        atomicAdd(&bnsum2[t], sQ[t]);
    }
}

__global__ void bn_final(const float* __restrict__ bnsum, const float* __restrict__ bnsum2,
                         const float* __restrict__ gamma_l, const float* __restrict__ beta_l,
                         float* __restrict__ sc_sh) {
    int f = threadIdx.x;
    if (f < FF) {
        float mu = bnsum[f] / (float)NN;
        float var = bnsum2[f] / (float)NN - mu * mu;
        var = fmaxf(var, 0.f);
        float s = gamma_l[f] * rsqrtf(var + EPSBN);
        sc_sh[f] = s;
        sc_sh[FF + f] = beta_l[f] - mu * s;
    }
}

__global__ void bn_apply(const float* __restrict__ out_pre, const float* __restrict__ sc_sh,
                         float* __restrict__ xout) {
    long i = (long)blockIdx.x * 256 + threadIdx.x;
    long stride = (long)gridDim.x * 256;
    for (long j = i; j < (long)NN * FF; j += stride) {
        int f = (int)(j & 63);
        float y = fmaf(out_pre[j], sc_sh[f], sc_sh[FF + f]);
        xout[j] = fmaxf(y, 0.f);
    }
}

extern "C" void kernel_launch(void* const* d_in, const int* in_sizes, int n_in,
                              void* d_out, int out_size, void* d_ws, size_t ws_size,
                              hipStream_t stream) {
    const float* x0    = (const float*)d_in[0];
    const int*   ei    = (const int*)d_in[1];
    const float* attr  = (const float*)d_in[2];
    const float* We    = (const float*)d_in[3];
    const float* be    = (const float*)d_in[4];
    const float* Wpre  = (const float*)d_in[5];
    const float* bpre  = (const float*)d_in[6];
    const float* Wpost = (const float*)d_in[7];
    const float* bpost = (const float*)d_in[8];
    const float* Wlin  = (const float*)d_in[9];
    const float* blin  = (const float*)d_in[10];
    const float* gamma = (const float*)d_in[11];
    const float* beta  = (const float*)d_in[12];
    float* out = (float*)d_out;

    char* ws = (char*)d_ws;
    size_t off = 0;
    auto carve = [&](size_t bytes) -> void* {
        void* p = ws + off;
        off += (bytes + 255) & ~(size_t)255;
        return p;
    };
    const size_t NFb = (size_t)NN * FF * 4;
    float*    Weff   = (float*)carve(2 * EDIM * FF * 4);
    float*    beff   = (float*)carve(2 * FF * 4);
    float*    Wc     = (float*)carve(2 * 7 * FF * FF * 4);
    float*    cfold  = (float*)carve(2 * FF * 4);
    short*    WpreF  = (short*)carve(2 * 4096 * 2);
    short*    WeffF  = (short*)carve(2 * 2048 * 2);
    short*    WcF    = (short*)carve(2 * 28672 * 2);
    int*      srcp   = (int*)carve(NE * 4);
    int*      perm   = (int*)carve(NE * 4);
    int*      rowptr = (int*)carve((NN + 1) * 4);
    int*      rowcnt = (int*)carve(NN * 4);
    int*      fill   = (int*)carve(NN * 4);
    int*      bc     = (int*)carve(NN * 4);
    float*    amp    = (float*)carve(NN * 4);
    short*    xpb    = (short*)carve((size_t)NN * FF * 2);
    short*    epc    = (short*)carve((size_t)ECH * FF * 2);   // 51.2 MB, also hosts out_pre
    float*    sumb   = (float*)carve(NFb);
    float*    mnb    = (float*)carve(NFb);
    float*    mxb    = (float*)carve(NFb);
    float*    xbuf   = (float*)carve(NFb);
    float*    bnsum  = (float*)carve(FF * 4);
    float*    bnsum2 = (float*)carve(FF * 4);
    float*    avglog = (float*)carve(4);
    float*    sc_sh  = (float*)carve(2 * FF * 4);
    float*    out_pre = (float*)epc;   // epc dead after last agg chunk of each layer

    const int EB = (int)((NE + 255) / 256);

    // one-time build
    build_zero<<<196, 256, 0, stream>>>(rowcnt, fill, bc, avglog);
    hist_dst<<<EB, 256, 0, stream>>>(ei, rowcnt);
    scan_kernel<<<1, 1024, 0, stream>>>(rowcnt, rowptr);
    scatter2<<<EB, 256, 0, stream>>>(ei, rowptr, fill, srcp, perm);
    degbc<<<196, 256, 0, stream>>>(rowcnt, bc);
    avglog_kernel<<<128, 256, 0, stream>>>(bc, avglog);
    amp_kernel<<<196, 256, 0, stream>>>(rowcnt, avglog, amp);
    fold_kernel<<<NLAYER, 256, 0, stream>>>(We, be, Wpre, bpre, Wpost, bpost, Wlin, blin,
                                            Weff, beff, Wc, cfold);
    for (int l = 0; l < NLAYER; ++l) {
        fragify<<<2, 256, 0, stream>>>(Wpre + (size_t)l * 2 * FF * FF, WpreF + l * 4096, 2, 64);
        fragify<<<1, 256, 0, stream>>>(Weff + (size_t)l * EDIM * FF, WeffF + l * 2048, 1, 16);
        fragify<<<14, 256, 0, stream>>>(Wc + (size_t)l * 7 * FF * FF, WcF + l * 28672, 14, 448);
    }

    for (int l = 0; l < NLAYER; ++l) {
        const float* xin = (l == 0) ? x0 : xbuf;
        float* xout = (l == NLAYER - 1) ? out : xbuf;

        init_layer<<<4096, 256, 0, stream>>>(sumb, mnb, mxb, bnsum, bnsum2);
        xp_mfma<<<(NGRP + 3) / 4, 256, 0, stream>>>(xin, WpreF + l * 4096, xpb);
        for (int c = 0; c < 2; ++c) {
            long elo = (long)c * ECH;
            ep_mfma<<<(int)(ECH / 16 / 4), 256, 0, stream>>>(attr, perm, WeffF + l * 2048,
                                                             beff + l * FF, epc, elo);
            agg_merge<<<12500, 256, 0, stream>>>(rowptr, srcp, xpb, epc, elo, elo + ECH,
                                                 sumb, mnb, mxb);
        }
        node_mfma<<<(NGRP + 3) / 4, 256, 0, stream>>>(xin, sumb, mnb, mxb, rowcnt, amp,
                                                      WcF + l * 28672, cfold + l * FF,
                                                      out_pre, bnsum, bnsum2);
        bn_final<<<1, 64, 0, stream>>>(bnsum, bnsum2, gamma + l * FF, beta + l * FF, sc_sh);
        bn_apply<<<4096, 256, 0, stream>>>(out_pre, sc_sh, xout);
    }
}

// Round 5
// 607.694 us; speedup vs baseline: 2.1781x; 1.3197x over previous
//
#include <hip/hip_runtime.h>
#include <math.h>

static constexpr int NN = 50000;     // nodes
static constexpr long NE = 800000;   // edges
static constexpr int FF = 64;        // features
static constexpr int EDIM = 16;      // edge attr dim
static constexpr int NLAYER = 2;
static constexpr float EPSBN = 1e-5f;
static constexpr int NGRP = NN / 16;         // 3125 node groups of 16
static constexpr long ECH = NE / 2;          // edge chunk (400000)

typedef __attribute__((ext_vector_type(8))) short short8v;
typedef __attribute__((ext_vector_type(4))) float f32x4;

#define MFMA16(a, b, c) __builtin_amdgcn_mfma_f32_16x16x32_bf16(a, b, c, 0, 0, 0)

__device__ __forceinline__ short f2bf(float f) {
    unsigned u = __float_as_uint(f);
    unsigned r = u + 0x7FFFu + ((u >> 16) & 1u);   // RNE
    return (short)(r >> 16);
}
__device__ __forceinline__ float bf2f(unsigned short h) {
    return __uint_as_float(((unsigned)h) << 16);
}
__device__ __forceinline__ short8v pack8(const float* p) {
    const float4* q = (const float4*)p;
    float4 a = q[0], b = q[1];
    short8v v;
    v[0] = f2bf(a.x); v[1] = f2bf(a.y); v[2] = f2bf(a.z); v[3] = f2bf(a.w);
    v[4] = f2bf(b.x); v[5] = f2bf(b.y); v[6] = f2bf(b.z); v[7] = f2bf(b.w);
    return v;
}
// split pack: hi = bf16(v), lo = bf16(v - hi)
__device__ __forceinline__ void pack8s(const float* p, short8v& hi, short8v& lo) {
    const float4* q = (const float4*)p;
    float4 a = q[0], b = q[1];
    float v[8] = {a.x, a.y, a.z, a.w, b.x, b.y, b.z, b.w};
#pragma unroll
    for (int j = 0; j < 8; ++j) {
        short h = f2bf(v[j]);
        hi[j] = h;
        lo[j] = f2bf(v[j] - bf2f((unsigned short)h));
    }
}
__device__ __forceinline__ void pack8fs(const float* v, short8v& hi, short8v& lo) {
#pragma unroll
    for (int j = 0; j < 8; ++j) {
        short h = f2bf(v[j]);
        hi[j] = h;
        lo[j] = f2bf(v[j] - bf2f((unsigned short)h));
    }
}

// ---- fold weights (32 blocks: 2 layers x 16 slices) ----
__global__ void fold_kernel(const float* __restrict__ We, const float* __restrict__ be,
                            const float* __restrict__ Wpre, const float* __restrict__ bpre,
                            const float* __restrict__ Wpost, const float* __restrict__ bpost,
                            const float* __restrict__ Wlin, const float* __restrict__ blin,
                            float* __restrict__ Weff, float* __restrict__ beff,
                            float* __restrict__ Wc, float* __restrict__ cfold) {
    int l = blockIdx.x >> 4;
    int s = blockIdx.x & 15;
    int t = threadIdx.x;
    const float* We_l    = We    + l * EDIM * FF;
    const float* Wpre_e  = Wpre  + l * 2 * FF * FF + FF * FF;  // rows 64..127
    const float* Wpost_l = Wpost + l * 7 * FF * FF;
    const float* Wlin_l  = Wlin  + l * FF * FF;

    __shared__ float slin[FF * FF];
    __shared__ float spre[FF * FF];
    for (int i = t; i < FF * FF; i += blockDim.x) { slin[i] = Wlin_l[i]; spre[i] = Wpre_e[i]; }
    __syncthreads();

    for (int i = s * 256 + t; i < EDIM * FF; i += 16 * 256) {
        int j = i >> 6, f = i & 63;
        float a = 0.f;
        for (int k = 0; k < FF; ++k) a += We_l[j * FF + k] * spre[k * FF + f];
        Weff[l * EDIM * FF + i] = a;
    }
    for (int i = s * 256 + t; i < FF; i += 16 * 256) {
        float a = bpre[l * FF + i];
        for (int k = 0; k < FF; ++k) a += be[l * FF + k] * spre[k * FF + i];
        beff[l * FF + i] = a;
    }
    for (int i = s * 256 + t; i < 7 * FF * FF; i += 16 * 256) {
        int r = i >> 6, f = i & 63;
        float a = 0.f;
        for (int k = 0; k < FF; ++k) a += Wpost_l[r * FF + k] * slin[k * FF + f];
        Wc[l * 7 * FF * FF + i] = a;
    }
    for (int i = s * 256 + t; i < FF; i += 16 * 256) {
        float a = blin[l * FF + i];
        for (int k = 0; k < FF; ++k) a += bpost[l * FF + k] * slin[k * FF + i];
        cfold[l * FF + i] = a;
    }
}

// ---- all weight fragments in one launch. 34 blocks: 2 layers x (2 Wpre + 1 Weff + 14 Wc)
__global__ void fragify_all(const float* __restrict__ Wpre, const float* __restrict__ Weff,
                            const float* __restrict__ Wc,
                            short* __restrict__ WpreF, short* __restrict__ WeffF,
                            short* __restrict__ WcFh, short* __restrict__ WcFl) {
    int b = blockIdx.x;          // 0..33
    int l = b / 17, r = b % 17;
    int t = threadIdx.x;
    const float* src; short* dh; short* dl = nullptr; int kc, Kreal;
    if (r < 2)      { src = Wpre + (size_t)l * 2 * FF * FF; dh = WpreF + l * 4096;  kc = r;     Kreal = 64; }
    else if (r < 3) { src = Weff + (size_t)l * EDIM * FF;   dh = WeffF + l * 2048;  kc = 0;     Kreal = 16; }
    else            { src = Wc   + (size_t)l * 7 * FF * FF; dh = WcFh + l * 28672;
                      dl = WcFl + l * 28672;                                        kc = r - 3; Kreal = 448; }
    int idx = kc * 256 + t;
    int lane = idx & 63, nt = (idx >> 6) & 3;
    int m = lane & 15, kh = lane >> 4;
    short8v hv, lv;
#pragma unroll
    for (int j = 0; j < 8; ++j) {
        int k = kc * 32 + kh * 8 + j;
        float val = (k < Kreal) ? src[k * FF + nt * 16 + m] : 0.f;
        short h = f2bf(val);
        hv[j] = h;
        lv[j] = f2bf(val - bf2f((unsigned short)h));
    }
    ((short8v*)dh)[idx] = hv;
    if (dl) ((short8v*)dl)[idx] = lv;
}

// ================= CSR build phase ==========

__global__ void build_zero(int* __restrict__ rowcnt, int* __restrict__ fill,
                           int* __restrict__ bc, float* __restrict__ avglog) {
    long i = (long)blockIdx.x * 256 + threadIdx.x;
    long stride = (long)gridDim.x * 256;
    for (long j = i; j < NN; j += stride) { rowcnt[j] = 0; fill[j] = 0; bc[j] = 0; }
    if (i == 0) avglog[0] = 0.f;
}

__global__ void hist_dst(const int* __restrict__ ei, int* __restrict__ rowcnt) {
    long e = (long)blockIdx.x * 256 + threadIdx.x;
    if (e < NE) atomicAdd(&rowcnt[ei[NE + e]], 1);
}

__global__ void scan_kernel(const int* __restrict__ rowcnt, int* __restrict__ rowptr) {
    __shared__ int part[1024];
    int t = threadIdx.x;
    const int CH = 49;
    int lo = t * CH, hi = lo + CH; if (hi > NN) hi = NN; if (lo > NN) lo = NN;
    int s = 0;
    for (int i = lo; i < hi; ++i) s += rowcnt[i];
    part[t] = s;
    __syncthreads();
    for (int o = 1; o < 1024; o <<= 1) {
        int v = (t >= o) ? part[t - o] : 0;
        __syncthreads();
        part[t] += v;
        __syncthreads();
    }
    int ex = (t == 0) ? 0 : part[t - 1];
    for (int i = lo; i < hi; ++i) { rowptr[i] = ex; ex += rowcnt[i]; }
    if (t == 1023) rowptr[NN] = part[1023];
}

__global__ void scatter2(const int* __restrict__ ei, const int* __restrict__ rowptr,
                         int* __restrict__ fill, int* __restrict__ srcp,
                         int* __restrict__ perm) {
    long e = (long)blockIdx.x * 256 + threadIdx.x;
    if (e >= NE) return;
    int d = ei[NE + e];
    int p = rowptr[d] + atomicAdd(&fill[d], 1);
    srcp[p] = ei[e];
    perm[p] = (int)e;
}

// LDS-privatized degree histogram (degrees cluster near E/N=16 -> global atomics serialize)
__global__ void degbc2(const int* __restrict__ rowcnt, int* __restrict__ bc) {
    __shared__ int h[256];
    int t = threadIdx.x;
    h[t] = 0;
    __syncthreads();
    for (long n = (long)blockIdx.x * 256 + t; n < NN; n += (long)gridDim.x * 256) {
        int d = rowcnt[n];
        if (d < 256) {
            atomicAdd(&h[d], 1);
        } else {
            if (d >= NN) d = NN - 1;
            atomicAdd(&bc[d], 1);
        }
    }
    __syncthreads();
    int v = h[t];
    if (v) atomicAdd(&bc[t], v);
}

__global__ void avglog_kernel(const int* __restrict__ bc, float* __restrict__ total) {
    float s = 0.f;
    for (long i = (long)blockIdx.x * 256 + threadIdx.x; i < NN; i += (long)gridDim.x * 256)
        s += logf((float)bc[i] + 1.f);
    for (int o = 32; o; o >>= 1) s += __shfl_down(s, o, 64);
    __shared__ float wsum[4];
    int lane = threadIdx.x & 63, wid = threadIdx.x >> 6;
    if (lane == 0) wsum[wid] = s;
    __syncthreads();
    if (threadIdx.x == 0) atomicAdd(total, wsum[0] + wsum[1] + wsum[2] + wsum[3]);
}

__global__ void amp_kernel(const int* __restrict__ cnt, const float* __restrict__ total,
                           float* __restrict__ amp) {
    long n = (long)blockIdx.x * 256 + threadIdx.x;
    if (n < NN) {
        float avg = total[0] / (float)NN;
        float sc = fmaxf((float)cnt[n], 1.f);
        amp[n] = logf(sc + 1.f) / avg;
    }
}

// ================= per-layer kernels ==========

// xp = x @ Wpre[0:64] -> bf16, via MFMA. wave per 16-node group. block 0 zeroes BN sums.
__global__ __launch_bounds__(256) void xp_mfma(const float* __restrict__ xin,
                                               const short* __restrict__ WF,
                                               short* __restrict__ xpb,
                                               float* __restrict__ bnsum,
                                               float* __restrict__ bnsum2) {
    int t = threadIdx.x;
    if (blockIdx.x == 0 && t < FF) { bnsum[t] = 0.f; bnsum2[t] = 0.f; }
    int g = blockIdx.x * 4 + (t >> 6);
    if (g >= NGRP) return;
    int lane = t & 63, m = lane & 15, kh = lane >> 4;
    const float* xr = xin + (long)(g * 16 + m) * FF;
    short8v a0 = pack8(xr + kh * 8);
    short8v a1 = pack8(xr + 32 + kh * 8);
    const short8v* BF = (const short8v*)WF;
    f32x4 acc[4];
#pragma unroll
    for (int nt = 0; nt < 4; ++nt) {
        f32x4 z = {0.f, 0.f, 0.f, 0.f};
        z = MFMA16(a0, BF[(0 * 4 + nt) * 64 + lane], z);
        z = MFMA16(a1, BF[(1 * 4 + nt) * 64 + lane], z);
        acc[nt] = z;
    }
#pragma unroll
    for (int nt = 0; nt < 4; ++nt)
#pragma unroll
        for (int r = 0; r < 4; ++r) {
            long node = g * 16 + kh * 4 + r;
            xpb[node * FF + nt * 16 + m] = f2bf(acc[nt][r]);
        }
}

// ep = attr[perm] @ Weff + beff -> bf16 (CSR-ordered, chunked). wave per 16 edges.
__global__ __launch_bounds__(256) void ep_mfma(const float* __restrict__ attr,
                                               const int* __restrict__ perm,
                                               const short* __restrict__ WF,
                                               const float* __restrict__ beff_l,
                                               short* __restrict__ epc, long elo) {
    int t = threadIdx.x;
    int g = blockIdx.x * 4 + (t >> 6);   // 0..ECH/16-1 (exact)
    int lane = t & 63, m = lane & 15, kh = lane >> 4;
    long p0 = elo + (long)g * 16;
    int orig = perm[p0 + m];
    short8v a;
    if (kh < 2) {
        a = pack8(attr + (long)orig * EDIM + kh * 8);
    } else {
#pragma unroll
        for (int j = 0; j < 8; ++j) a[j] = 0;
    }
    const short8v* BF = (const short8v*)WF;
    float bfv[4];
#pragma unroll
    for (int nt = 0; nt < 4; ++nt) bfv[nt] = beff_l[nt * 16 + m];
    f32x4 acc[4];
#pragma unroll
    for (int nt = 0; nt < 4; ++nt) {
        f32x4 z = {0.f, 0.f, 0.f, 0.f};
        acc[nt] = MFMA16(a, BF[nt * 64 + lane], z);
    }
#pragma unroll
    for (int nt = 0; nt < 4; ++nt)
#pragma unroll
        for (int r = 0; r < 4; ++r) {
            long rel = (long)g * 16 + kh * 4 + r;
            epc[rel * FF + nt * 16 + m] = f2bf(acc[nt][r] + bfv[nt]);
        }
}

// CSR aggregation over edge chunk [elo,ehi): h = xp[src] + ep.
// first=1: WRITE results (identity values when empty) -> no init pass needed.
__global__ __launch_bounds__(256) void agg_merge(
    const int* __restrict__ rowptr, const int* __restrict__ srcp,
    const short* __restrict__ xpb, const short* __restrict__ epc,
    long elo, long ehi, int first,
    float* __restrict__ sumb, float* __restrict__ mnb, float* __restrict__ mxb) {
    int t = threadIdx.x;
    int n = blockIdx.x * 4 + (t >> 6);
    if (n >= NN) return;
    int lane = t & 63;
    long r0 = rowptr[n], r1 = rowptr[n + 1];
    long lo = r0 > elo ? r0 : elo;
    long hi = r1 < ehi ? r1 : ehi;
    const float INF = __builtin_huge_valf();
    float sm = 0.f, mn = INF, mx = -INF;
    if (!first && lo >= hi) return;
    if (lo < hi) {
        const unsigned short* xu = (const unsigned short*)xpb;
        const unsigned short* eu = (const unsigned short*)epc;
        int s = srcp[lo];
        float xv = bf2f(xu[(long)s * FF + lane]);
        float ev = bf2f(eu[(lo - elo) * FF + lane]);
        for (long e = lo; e < hi; ++e) {
            float h = xv + ev;
            if (e + 1 < hi) {
                int s2 = srcp[e + 1];
                xv = bf2f(xu[(long)s2 * FF + lane]);
                ev = bf2f(eu[(e + 1 - elo) * FF + lane]);
            }
            sm += h;
            mn = fminf(mn, h);
            mx = fmaxf(mx, h);
        }
    }
    long o = (long)n * FF + lane;
    if (first) {
        sumb[o] = sm; mnb[o] = mn; mxb[o] = mx;
    } else {
        sumb[o] += sm;
        mnb[o] = fminf(mnb[o], mn);
        mxb[o] = fmaxf(mxb[o], mx);
    }
}

// node GEMM via split-bf16 MFMA (3 MFMA per frag: ah*bh + al*bh + ah*bl).
__global__ __launch_bounds__(256) void node_mfma(
    const float* __restrict__ xin, const float* __restrict__ sumb,
    const float* __restrict__ mnb, const float* __restrict__ mxb,
    const int* __restrict__ rowcnt, const float* __restrict__ amp,
    const short* __restrict__ WFh, const short* __restrict__ WFl,
    const float* __restrict__ cfold_l,
    float* __restrict__ out_pre, float* __restrict__ bnsum, float* __restrict__ bnsum2) {
    __shared__ float sS[FF], sQ[FF];
    int t = threadIdx.x;
    if (t < FF) { sS[t] = 0.f; sQ[t] = 0.f; }
    __syncthreads();
    int g = blockIdx.x * 4 + (t >> 6);
    bool act = (g < NGRP);
    int lane = t & 63, m = lane & 15, kh = lane >> 4;
    if (act) {
        long n = g * 16 + m;
        int deg = rowcnt[n];
        float inv = 1.f / fmaxf((float)deg, 1.f);
        bool has = (deg > 0);
        float av = amp[n];
        const float* xr = xin + n * FF;
        float vme[16], vmn[16], vmx[16], sc16[16];
        {
            const float4* s4a = (const float4*)(sumb + n * FF + kh * 8);
            const float4* s4b = (const float4*)(sumb + n * FF + 32 + kh * 8);
            float4 a = s4a[0], b = s4a[1], c = s4b[0], d = s4b[1];
            vme[0]=a.x*inv; vme[1]=a.y*inv; vme[2]=a.z*inv; vme[3]=a.w*inv;
            vme[4]=b.x*inv; vme[5]=b.y*inv; vme[6]=b.z*inv; vme[7]=b.w*inv;
            vme[8]=c.x*inv; vme[9]=c.y*inv; vme[10]=c.z*inv; vme[11]=c.w*inv;
            vme[12]=d.x*inv; vme[13]=d.y*inv; vme[14]=d.z*inv; vme[15]=d.w*inv;
        }
        {
            const float4* s4a = (const float4*)(mnb + n * FF + kh * 8);
            const float4* s4b = (const float4*)(mnb + n * FF + 32 + kh * 8);
            float4 a = s4a[0], b = s4a[1], c = s4b[0], d = s4b[1];
            vmn[0]=has?a.x:0.f; vmn[1]=has?a.y:0.f; vmn[2]=has?a.z:0.f; vmn[3]=has?a.w:0.f;
            vmn[4]=has?b.x:0.f; vmn[5]=has?b.y:0.f; vmn[6]=has?b.z:0.f; vmn[7]=has?b.w:0.f;
            vmn[8]=has?c.x:0.f; vmn[9]=has?c.y:0.f; vmn[10]=has?c.z:0.f; vmn[11]=has?c.w:0.f;
            vmn[12]=has?d.x:0.f; vmn[13]=has?d.y:0.f; vmn[14]=has?d.z:0.f; vmn[15]=has?d.w:0.f;
        }
        {
            const float4* s4a = (const float4*)(mxb + n * FF + kh * 8);
            const float4* s4b = (const float4*)(mxb + n * FF + 32 + kh * 8);
            float4 a = s4a[0], b = s4a[1], c = s4b[0], d = s4b[1];
            vmx[0]=has?a.x:0.f; vmx[1]=has?a.y:0.f; vmx[2]=has?a.z:0.f; vmx[3]=has?a.w:0.f;
            vmx[4]=has?b.x:0.f; vmx[5]=has?b.y:0.f; vmx[6]=has?b.z:0.f; vmx[7]=has?b.w:0.f;
            vmx[8]=has?c.x:0.f; vmx[9]=has?c.y:0.f; vmx[10]=has?c.z:0.f; vmx[11]=has?c.w:0.f;
            vmx[12]=has?d.x:0.f; vmx[13]=has?d.y:0.f; vmx[14]=has?d.z:0.f; vmx[15]=has?d.w:0.f;
        }
        const short8v* BH = (const short8v*)WFh;
        const short8v* BL = (const short8v*)WFl;
        f32x4 acc[4];
#pragma unroll
        for (int nt = 0; nt < 4; ++nt) { f32x4 z = {0.f,0.f,0.f,0.f}; acc[nt] = z; }
        short8v hv, lv;
#define DO_KC3(kc) { \
        _Pragma("unroll") for (int nt = 0; nt < 4; ++nt) { \
            acc[nt] = MFMA16(hv, BH[((kc) * 4 + nt) * 64 + lane], acc[nt]); \
            acc[nt] = MFMA16(lv, BH[((kc) * 4 + nt) * 64 + lane], acc[nt]); \
            acc[nt] = MFMA16(hv, BL[((kc) * 4 + nt) * 64 + lane], acc[nt]); } }
        pack8s(xr + kh * 8, hv, lv);        DO_KC3(0)
        pack8s(xr + 32 + kh * 8, hv, lv);   DO_KC3(1)
        pack8fs(vme + 0, hv, lv);           DO_KC3(2)
        pack8fs(vme + 8, hv, lv);           DO_KC3(3)
        pack8fs(vmn + 0, hv, lv);           DO_KC3(4)
        pack8fs(vmn + 8, hv, lv);           DO_KC3(5)
        pack8fs(vmx + 0, hv, lv);           DO_KC3(6)
        pack8fs(vmx + 8, hv, lv);           DO_KC3(7)
#pragma unroll
        for (int j = 0; j < 16; ++j) sc16[j] = vme[j] * av;
        pack8fs(sc16 + 0, hv, lv);          DO_KC3(8)
        pack8fs(sc16 + 8, hv, lv);          DO_KC3(9)
#pragma unroll
        for (int j = 0; j < 16; ++j) sc16[j] = vmn[j] * av;
        pack8fs(sc16 + 0, hv, lv);          DO_KC3(10)
        pack8fs(sc16 + 8, hv, lv);          DO_KC3(11)
#pragma unroll
        for (int j = 0; j < 16; ++j) sc16[j] = vmx[j] * av;
        pack8fs(sc16 + 0, hv, lv);          DO_KC3(12)
        pack8fs(sc16 + 8, hv, lv);          DO_KC3(13)
#undef DO_KC3
        float cfv[4];
#pragma unroll
        for (int nt = 0; nt < 4; ++nt) cfv[nt] = cfold_l[nt * 16 + m];
#pragma unroll
        for (int nt = 0; nt < 4; ++nt) {
            float ps = 0.f, pq = 0.f;
#pragma unroll
            for (int r = 0; r < 4; ++r) {
                float v = acc[nt][r] + cfv[nt];
                out_pre[(long)(g * 16 + kh * 4 + r) * FF + nt * 16 + m] = v;
                ps += v;
                pq += v * v;
            }
            atomicAdd(&sS[nt * 16 + m], ps);
            atomicAdd(&sQ[nt * 16 + m], pq);
        }
    }
    __syncthreads();
    if (t < FF) {
        atomicAdd(&bnsum[t], sS[t]);
        atomicAdd(&bnsum2[t], sQ[t]);
    }
}

// BN finalize + apply + ReLU in one kernel
__global__ void bn_apply2(const float* __restrict__ out_pre,
                          const float* __restrict__ bnsum, const float* __restrict__ bnsum2,
                          const float* __restrict__ gamma_l, const float* __restrict__ beta_l,
                          float* __restrict__ xout) {
    int f = threadIdx.x & 63;
    float mu = bnsum[f] / (float)NN;
    float var = bnsum2[f] / (float)NN - mu * mu;
    var = fmaxf(var, 0.f);
    float s = gamma_l[f] * rsqrtf(var + EPSBN);
    float o = beta_l[f] - mu * s;
    long i = (long)blockIdx.x * 256 + threadIdx.x;
    long stride = (long)gridDim.x * 256;   // multiple of 64 -> (j & 63) == f invariant
    for (long j = i; j < (long)NN * FF; j += stride) {
        xout[j] = fmaxf(fmaf(out_pre[j], s, o), 0.f);
    }
}

extern "C" void kernel_launch(void* const* d_in, const int* in_sizes, int n_in,
                              void* d_out, int out_size, void* d_ws, size_t ws_size,
                              hipStream_t stream) {
    const float* x0    = (const float*)d_in[0];
    const int*   ei    = (const int*)d_in[1];
    const float* attr  = (const float*)d_in[2];
    const float* We    = (const float*)d_in[3];
    const float* be    = (const float*)d_in[4];
    const float* Wpre  = (const float*)d_in[5];
    const float* bpre  = (const float*)d_in[6];
    const float* Wpost = (const float*)d_in[7];
    const float* bpost = (const float*)d_in[8];
    const float* Wlin  = (const float*)d_in[9];
    const float* blin  = (const float*)d_in[10];
    const float* gamma = (const float*)d_in[11];
    const float* beta  = (const float*)d_in[12];
    float* out = (float*)d_out;

    char* ws = (char*)d_ws;
    size_t off = 0;
    auto carve = [&](size_t bytes) -> void* {
        void* p = ws + off;
        off += (bytes + 255) & ~(size_t)255;
        return p;
    };
    const size_t NFb = (size_t)NN * FF * 4;
    float*    Weff   = (float*)carve(2 * EDIM * FF * 4);
    float*    beff   = (float*)carve(2 * FF * 4);
    float*    Wc     = (float*)carve(2 * 7 * FF * FF * 4);
    float*    cfold  = (float*)carve(2 * FF * 4);
    short*    WpreF  = (short*)carve(2 * 4096 * 2);
    short*    WeffF  = (short*)carve(2 * 2048 * 2);
    short*    WcFh   = (short*)carve(2 * 28672 * 2);
    short*    WcFl   = (short*)carve(2 * 28672 * 2);
    int*      srcp   = (int*)carve(NE * 4);
    int*      perm   = (int*)carve(NE * 4);
    int*      rowptr = (int*)carve((NN + 1) * 4);
    int*      rowcnt = (int*)carve(NN * 4);
    int*      fill   = (int*)carve(NN * 4);
    int*      bc     = (int*)carve(NN * 4);
    float*    amp    = (float*)carve(NN * 4);
    short*    xpb    = (short*)carve((size_t)NN * FF * 2);
    short*    epc    = (short*)carve((size_t)ECH * FF * 2);   // 51.2 MB, also hosts out_pre
    float*    sumb   = (float*)carve(NFb);
    float*    mnb    = (float*)carve(NFb);
    float*    mxb    = (float*)carve(NFb);
    float*    xbuf   = (float*)carve(NFb);
    float*    bnsum  = (float*)carve(FF * 4);
    float*    bnsum2 = (float*)carve(FF * 4);
    float*    avglog = (float*)carve(4);
    float*    out_pre = (float*)epc;   // epc dead after last agg chunk of each layer

    const int EB = (int)((NE + 255) / 256);

    // one-time build
    build_zero<<<196, 256, 0, stream>>>(rowcnt, fill, bc, avglog);
    hist_dst<<<EB, 256, 0, stream>>>(ei, rowcnt);
    scan_kernel<<<1, 1024, 0, stream>>>(rowcnt, rowptr);
    scatter2<<<EB, 256, 0, stream>>>(ei, rowptr, fill, srcp, perm);
    degbc2<<<196, 256, 0, stream>>>(rowcnt, bc);
    avglog_kernel<<<128, 256, 0, stream>>>(bc, avglog);
    amp_kernel<<<196, 256, 0, stream>>>(rowcnt, avglog, amp);
    fold_kernel<<<32, 256, 0, stream>>>(We, be, Wpre, bpre, Wpost, bpost, Wlin, blin,
                                        Weff, beff, Wc, cfold);
    fragify_all<<<34, 256, 0, stream>>>(Wpre, Weff, Wc, WpreF, WeffF, WcFh, WcFl);

    for (int l = 0; l < NLAYER; ++l) {
        const float* xin = (l == 0) ? x0 : xbuf;
        float* xout = (l == NLAYER - 1) ? out : xbuf;

        xp_mfma<<<(NGRP + 3) / 4, 256, 0, stream>>>(xin, WpreF + l * 4096, xpb, bnsum, bnsum2);
        for (int c = 0; c < 2; ++c) {
            long elo = (long)c * ECH;
            ep_mfma<<<(int)(ECH / 16 / 4), 256, 0, stream>>>(attr, perm, WeffF + l * 2048,
                                                             beff + l * FF, epc, elo);
            agg_merge<<<12500, 256, 0, stream>>>(rowptr, srcp, xpb, epc, elo, elo + ECH,
                                                 (c == 0) ? 1 : 0, sumb, mnb, mxb);
        }
        node_mfma<<<(NGRP + 3) / 4, 256, 0, stream>>>(xin, sumb, mnb, mxb, rowcnt, amp,
                                                      WcFh + l * 28672, WcFl + l * 28672,
                                                      cfold + l * FF,
                                                      out_pre, bnsum, bnsum2);
        bn_apply2<<<4096, 256, 0, stream>>>(out_pre, bnsum, bnsum2,
                                            gamma + l * FF, beta + l * FF, xout);
    }
}

// Round 6
// 487.467 us; speedup vs baseline: 2.7153x; 1.2466x over previous
//
#include <hip/hip_runtime.h>
#include <math.h>

static constexpr int NN = 50000;     // nodes
static constexpr long NE = 800000;   // edges
static constexpr int FF = 64;        // features
static constexpr int EDIM = 16;      // edge attr dim
static constexpr int NLAYER = 2;
static constexpr float EPSBN = 1e-5f;
static constexpr int NGRP = NN / 16;         // 3125 node groups of 16
static constexpr int SCB = 512;              // scan block size
static constexpr int NSCB = (NN + SCB - 1) / SCB;  // 98

typedef __attribute__((ext_vector_type(8))) short short8v;
typedef __attribute__((ext_vector_type(4))) float f32x4;

#define MFMA16(a, b, c) __builtin_amdgcn_mfma_f32_16x16x32_bf16(a, b, c, 0, 0, 0)

__device__ __forceinline__ short f2bf(float f) {
    unsigned u = __float_as_uint(f);
    unsigned r = u + 0x7FFFu + ((u >> 16) & 1u);   // RNE
    return (short)(r >> 16);
}
__device__ __forceinline__ float bf2f(unsigned short h) {
    return __uint_as_float(((unsigned)h) << 16);
}
__device__ __forceinline__ short8v pack8(const float* p) {
    const float4* q = (const float4*)p;
    float4 a = q[0], b = q[1];
    short8v v;
    v[0] = f2bf(a.x); v[1] = f2bf(a.y); v[2] = f2bf(a.z); v[3] = f2bf(a.w);
    v[4] = f2bf(b.x); v[5] = f2bf(b.y); v[6] = f2bf(b.z); v[7] = f2bf(b.w);
    return v;
}
// split pack: hi = bf16(v), lo = bf16(v - hi)
__device__ __forceinline__ void pack8s(const float* p, short8v& hi, short8v& lo) {
    const float4* q = (const float4*)p;
    float4 a = q[0], b = q[1];
    float v[8] = {a.x, a.y, a.z, a.w, b.x, b.y, b.z, b.w};
#pragma unroll
    for (int j = 0; j < 8; ++j) {
        short h = f2bf(v[j]);
        hi[j] = h;
        lo[j] = f2bf(v[j] - bf2f((unsigned short)h));
    }
}
__device__ __forceinline__ void pack8fs(const float* v, short8v& hi, short8v& lo) {
#pragma unroll
    for (int j = 0; j < 8; ++j) {
        short h = f2bf(v[j]);
        hi[j] = h;
        lo[j] = f2bf(v[j] - bf2f((unsigned short)h));
    }
}

// ---- fold weights (32 blocks: 2 layers x 16 slices) ----
__global__ void fold_kernel(const float* __restrict__ We, const float* __restrict__ be,
                            const float* __restrict__ Wpre, const float* __restrict__ bpre,
                            const float* __restrict__ Wpost, const float* __restrict__ bpost,
                            const float* __restrict__ Wlin, const float* __restrict__ blin,
                            float* __restrict__ Weff, float* __restrict__ beff,
                            float* __restrict__ Wc, float* __restrict__ cfold) {
    int l = blockIdx.x >> 4;
    int s = blockIdx.x & 15;
    int t = threadIdx.x;
    const float* We_l    = We    + l * EDIM * FF;
    const float* Wpre_e  = Wpre  + l * 2 * FF * FF + FF * FF;  // rows 64..127
    const float* Wpost_l = Wpost + l * 7 * FF * FF;
    const float* Wlin_l  = Wlin  + l * FF * FF;

    __shared__ float slin[FF * FF];
    __shared__ float spre[FF * FF];
    for (int i = t; i < FF * FF; i += blockDim.x) { slin[i] = Wlin_l[i]; spre[i] = Wpre_e[i]; }
    __syncthreads();

    for (int i = s * 256 + t; i < EDIM * FF; i += 16 * 256) {
        int j = i >> 6, f = i & 63;
        float a = 0.f;
        for (int k = 0; k < FF; ++k) a += We_l[j * FF + k] * spre[k * FF + f];
        Weff[l * EDIM * FF + i] = a;
    }
    for (int i = s * 256 + t; i < FF; i += 16 * 256) {
        float a = bpre[l * FF + i];
        for (int k = 0; k < FF; ++k) a += be[l * FF + k] * spre[k * FF + i];
        beff[l * FF + i] = a;
    }
    for (int i = s * 256 + t; i < 7 * FF * FF; i += 16 * 256) {
        int r = i >> 6, f = i & 63;
        float a = 0.f;
        for (int k = 0; k < FF; ++k) a += Wpost_l[r * FF + k] * slin[k * FF + f];
        Wc[l * 7 * FF * FF + i] = a;
    }
    for (int i = s * 256 + t; i < FF; i += 16 * 256) {
        float a = blin[l * FF + i];
        for (int k = 0; k < FF; ++k) a += bpost[l * FF + k] * slin[k * FF + i];
        cfold[l * FF + i] = a;
    }
}

// ---- all weight fragments in one launch. 34 blocks: 2 layers x (2 Wpre + 1 Weff + 14 Wc)
__global__ void fragify_all(const float* __restrict__ Wpre, const float* __restrict__ Weff,
                            const float* __restrict__ Wc,
                            short* __restrict__ WpreF, short* __restrict__ WeffF,
                            short* __restrict__ WcFh, short* __restrict__ WcFl) {
    int b = blockIdx.x;          // 0..33
    int l = b / 17, r = b % 17;
    int t = threadIdx.x;
    const float* src; short* dh; short* dl = nullptr; int kc, Kreal;
    if (r < 2)      { src = Wpre + (size_t)l * 2 * FF * FF; dh = WpreF + l * 4096;  kc = r;     Kreal = 64; }
    else if (r < 3) { src = Weff + (size_t)l * EDIM * FF;   dh = WeffF + l * 2048;  kc = 0;     Kreal = 16; }
    else            { src = Wc   + (size_t)l * 7 * FF * FF; dh = WcFh + l * 28672;
                      dl = WcFl + l * 28672;                                        kc = r - 3; Kreal = 448; }
    int idx = kc * 256 + t;
    int lane = idx & 63, nt = (idx >> 6) & 3;
    int m = lane & 15, kh = lane >> 4;
    short8v hv, lv;
#pragma unroll
    for (int j = 0; j < 8; ++j) {
        int k = kc * 32 + kh * 8 + j;
        float val = (k < Kreal) ? src[k * FF + nt * 16 + m] : 0.f;
        short h = f2bf(val);
        hv[j] = h;
        lv[j] = f2bf(val - bf2f((unsigned short)h));
    }
    ((short8v*)dh)[idx] = hv;
    if (dl) ((short8v*)dl)[idx] = lv;
}

// ================= CSR build phase ==========

__global__ void build_zero(int* __restrict__ rowcnt, int* __restrict__ fill,
                           int* __restrict__ bc, float* __restrict__ avglog) {
    long i = (long)blockIdx.x * 256 + threadIdx.x;
    long stride = (long)gridDim.x * 256;
    for (long j = i; j < NN; j += stride) { rowcnt[j] = 0; fill[j] = 0; bc[j] = 0; }
    if (i == 0) avglog[0] = 0.f;
}

__global__ void hist_dst(const int* __restrict__ ei, int* __restrict__ rowcnt) {
    long e = (long)blockIdx.x * 256 + threadIdx.x;
    if (e < NE) atomicAdd(&rowcnt[ei[NE + e]], 1);
}

// ---- hierarchical exclusive scan: rowcnt[NN] -> rowptr[NN+1] ----
__global__ void scan_a(const int* __restrict__ rowcnt, int* __restrict__ part) {
    __shared__ int red[SCB];
    int t = threadIdx.x;
    int i = blockIdx.x * SCB + t;
    red[t] = (i < NN) ? rowcnt[i] : 0;
    __syncthreads();
    for (int o = SCB / 2; o > 0; o >>= 1) {
        if (t < o) red[t] += red[t + o];
        __syncthreads();
    }
    if (t == 0) part[blockIdx.x] = red[0];
}

__global__ void scan_b(int* __restrict__ part, int* __restrict__ rowptr) {
    __shared__ int s[128];
    int t = threadIdx.x;
    int v = (t < NSCB) ? part[t] : 0;
    s[t] = v;
    __syncthreads();
    for (int o = 1; o < 128; o <<= 1) {
        int u = (t >= o) ? s[t - o] : 0;
        __syncthreads();
        s[t] += u;
        __syncthreads();
    }
    if (t < NSCB) part[t] = s[t] - v;          // exclusive block offset
    if (t == 127) rowptr[NN] = s[127];         // total
}

__global__ void scan_c(const int* __restrict__ rowcnt, const int* __restrict__ part,
                       int* __restrict__ rowptr) {
    __shared__ int s[SCB];
    int t = threadIdx.x;
    int i = blockIdx.x * SCB + t;
    int v = (i < NN) ? rowcnt[i] : 0;
    s[t] = v;
    __syncthreads();
    for (int o = 1; o < SCB; o <<= 1) {
        int u = (t >= o) ? s[t - o] : 0;
        __syncthreads();
        s[t] += u;
        __syncthreads();
    }
    if (i < NN) rowptr[i] = part[blockIdx.x] + s[t] - v;
}

__global__ void scatter2(const int* __restrict__ ei, const int* __restrict__ rowptr,
                         int* __restrict__ fill, int* __restrict__ srcp,
                         int* __restrict__ perm) {
    long e = (long)blockIdx.x * 256 + threadIdx.x;
    if (e >= NE) return;
    int d = ei[NE + e];
    int p = rowptr[d] + atomicAdd(&fill[d], 1);
    srcp[p] = ei[e];
    perm[p] = (int)e;
}

// LDS-privatized degree histogram
__global__ void degbc2(const int* __restrict__ rowcnt, int* __restrict__ bc) {
    __shared__ int h[256];
    int t = threadIdx.x;
    h[t] = 0;
    __syncthreads();
    for (long n = (long)blockIdx.x * 256 + t; n < NN; n += (long)gridDim.x * 256) {
        int d = rowcnt[n];
        if (d < 256) {
            atomicAdd(&h[d], 1);
        } else {
            if (d >= NN) d = NN - 1;
            atomicAdd(&bc[d], 1);
        }
    }
    __syncthreads();
    int v = h[t];
    if (v) atomicAdd(&bc[t], v);
}

__global__ void avglog_kernel(const int* __restrict__ bc, float* __restrict__ total) {
    float s = 0.f;
    for (long i = (long)blockIdx.x * 256 + threadIdx.x; i < NN; i += (long)gridDim.x * 256)
        s += logf((float)bc[i] + 1.f);
    for (int o = 32; o; o >>= 1) s += __shfl_down(s, o, 64);
    __shared__ float wsum[4];
    int lane = threadIdx.x & 63, wid = threadIdx.x >> 6;
    if (lane == 0) wsum[wid] = s;
    __syncthreads();
    if (threadIdx.x == 0) atomicAdd(total, wsum[0] + wsum[1] + wsum[2] + wsum[3]);
}

__global__ void amp_kernel(const int* __restrict__ cnt, const float* __restrict__ total,
                           float* __restrict__ amp) {
    long n = (long)blockIdx.x * 256 + threadIdx.x;
    if (n < NN) {
        float avg = total[0] / (float)NN;
        float sc = fmaxf((float)cnt[n], 1.f);
        amp[n] = logf(sc + 1.f) / avg;
    }
}

// ================= per-layer kernels ==========

// xp = x @ Wpre[0:64] -> bf16, via MFMA. wave per 16-node group. block 0 zeroes BN sums.
__global__ __launch_bounds__(256) void xp_mfma(const float* __restrict__ xin,
                                               const short* __restrict__ WF,
                                               short* __restrict__ xpb,
                                               float* __restrict__ bnsum,
                                               float* __restrict__ bnsum2) {
    int t = threadIdx.x;
    if (blockIdx.x == 0 && t < FF) { bnsum[t] = 0.f; bnsum2[t] = 0.f; }
    int g = blockIdx.x * 4 + (t >> 6);
    if (g >= NGRP) return;
    int lane = t & 63, m = lane & 15, kh = lane >> 4;
    const float* xr = xin + (long)(g * 16 + m) * FF;
    short8v a0 = pack8(xr + kh * 8);
    short8v a1 = pack8(xr + 32 + kh * 8);
    const short8v* BF = (const short8v*)WF;
    f32x4 acc[4];
#pragma unroll
    for (int nt = 0; nt < 4; ++nt) {
        f32x4 z = {0.f, 0.f, 0.f, 0.f};
        z = MFMA16(a0, BF[(0 * 4 + nt) * 64 + lane], z);
        z = MFMA16(a1, BF[(1 * 4 + nt) * 64 + lane], z);
        acc[nt] = z;
    }
#pragma unroll
    for (int nt = 0; nt < 4; ++nt)
#pragma unroll
        for (int r = 0; r < 4; ++r) {
            long node = g * 16 + kh * 4 + r;
            xpb[node * FF + nt * 16 + m] = f2bf(acc[nt][r]);
        }
}

// ep = attr[perm] @ Weff + beff -> bf16 (CSR-ordered, chunked). wave per 16 edges.
__global__ __launch_bounds__(256) void ep_mfma(const float* __restrict__ attr,
                                               const int* __restrict__ perm,
                                               const short* __restrict__ WF,
                                               const float* __restrict__ beff_l,
                                               short* __restrict__ epc, long elo) {
    int t = threadIdx.x;
    int g = blockIdx.x * 4 + (t >> 6);
    int lane = t & 63, m = lane & 15, kh = lane >> 4;
    long p0 = elo + (long)g * 16;
    int orig = perm[p0 + m];
    short8v a;
    if (kh < 2) {
        a = pack8(attr + (long)orig * EDIM + kh * 8);
    } else {
#pragma unroll
        for (int j = 0; j < 8; ++j) a[j] = 0;
    }
    const short8v* BF = (const short8v*)WF;
    float bfv[4];
#pragma unroll
    for (int nt = 0; nt < 4; ++nt) bfv[nt] = beff_l[nt * 16 + m];
    f32x4 acc[4];
#pragma unroll
    for (int nt = 0; nt < 4; ++nt) {
        f32x4 z = {0.f, 0.f, 0.f, 0.f};
        acc[nt] = MFMA16(a, BF[nt * 64 + lane], z);
    }
#pragma unroll
    for (int nt = 0; nt < 4; ++nt)
#pragma unroll
        for (int r = 0; r < 4; ++r) {
            long rel = (long)g * 16 + kh * 4 + r;
            epc[rel * FF + nt * 16 + m] = f2bf(acc[nt][r] + bfv[nt]);
        }
}

// CSR aggregation over edge chunk [elo,ehi): h = xp[src] + ep.
// first=1: WRITE results (identity values when empty) -> no init pass needed.
__global__ __launch_bounds__(256) void agg_merge(
    const int* __restrict__ rowptr, const int* __restrict__ srcp,
    const short* __restrict__ xpb, const short* __restrict__ epc,
    long elo, long ehi, int first,
    float* __restrict__ sumb, float* __restrict__ mnb, float* __restrict__ mxb) {
    int t = threadIdx.x;
    int n = blockIdx.x * 4 + (t >> 6);
    if (n >= NN) return;
    int lane = t & 63;
    long r0 = rowptr[n], r1 = rowptr[n + 1];
    long lo = r0 > elo ? r0 : elo;
    long hi = r1 < ehi ? r1 : ehi;
    const float INF = __builtin_huge_valf();
    float sm = 0.f, mn = INF, mx = -INF;
    if (!first && lo >= hi) return;
    if (lo < hi) {
        const unsigned short* xu = (const unsigned short*)xpb;
        const unsigned short* eu = (const unsigned short*)epc;
        int s = srcp[lo];
        float xv = bf2f(xu[(long)s * FF + lane]);
        float ev = bf2f(eu[(lo - elo) * FF + lane]);
        for (long e = lo; e < hi; ++e) {
            float h = xv + ev;
            if (e + 1 < hi) {
                int s2 = srcp[e + 1];
                xv = bf2f(xu[(long)s2 * FF + lane]);
                ev = bf2f(eu[(e + 1 - elo) * FF + lane]);
            }
            sm += h;
            mn = fminf(mn, h);
            mx = fmaxf(mx, h);
        }
    }
    long o = (long)n * FF + lane;
    if (first) {
        sumb[o] = sm; mnb[o] = mn; mxb[o] = mx;
    } else {
        sumb[o] += sm;
        mnb[o] = fminf(mnb[o], mn);
        mxb[o] = fmaxf(mxb[o], mx);
    }
}

// node GEMM via split-bf16 MFMA (3 MFMA per frag: ah*bh + al*bh + ah*bl).
__global__ __launch_bounds__(256) void node_mfma(
    const float* __restrict__ xin, const float* __restrict__ sumb,
    const float* __restrict__ mnb, const float* __restrict__ mxb,
    const int* __restrict__ rowcnt, const float* __restrict__ amp,
    const short* __restrict__ WFh, const short* __restrict__ WFl,
    const float* __restrict__ cfold_l,
    float* __restrict__ out_pre, float* __restrict__ bnsum, float* __restrict__ bnsum2) {
    __shared__ float sS[FF], sQ[FF];
    int t = threadIdx.x;
    if (t < FF) { sS[t] = 0.f; sQ[t] = 0.f; }
    __syncthreads();
    int g = blockIdx.x * 4 + (t >> 6);
    bool act = (g < NGRP);
    int lane = t & 63, m = lane & 15, kh = lane >> 4;
    if (act) {
        long n = g * 16 + m;
        int deg = rowcnt[n];
        float inv = 1.f / fmaxf((float)deg, 1.f);
        bool has = (deg > 0);
        float av = amp[n];
        const float* xr = xin + n * FF;
        float vme[16], vmn[16], vmx[16], sc16[16];
        {
            const float4* s4a = (const float4*)(sumb + n * FF + kh * 8);
            const float4* s4b = (const float4*)(sumb + n * FF + 32 + kh * 8);
            float4 a = s4a[0], b = s4a[1], c = s4b[0], d = s4b[1];
            vme[0]=a.x*inv; vme[1]=a.y*inv; vme[2]=a.z*inv; vme[3]=a.w*inv;
            vme[4]=b.x*inv; vme[5]=b.y*inv; vme[6]=b.z*inv; vme[7]=b.w*inv;
            vme[8]=c.x*inv; vme[9]=c.y*inv; vme[10]=c.z*inv; vme[11]=c.w*inv;
            vme[12]=d.x*inv; vme[13]=d.y*inv; vme[14]=d.z*inv; vme[15]=d.w*inv;
        }
        {
            const float4* s4a = (const float4*)(mnb + n * FF + kh * 8);
            const float4* s4b = (const float4*)(mnb + n * FF + 32 + kh * 8);
            float4 a = s4a[0], b = s4a[1], c = s4b[0], d = s4b[1];
            vmn[0]=has?a.x:0.f; vmn[1]=has?a.y:0.f; vmn[2]=has?a.z:0.f; vmn[3]=has?a.w:0.f;
            vmn[4]=has?b.x:0.f; vmn[5]=has?b.y:0.f; vmn[6]=has?b.z:0.f; vmn[7]=has?b.w:0.f;
            vmn[8]=has?c.x:0.f; vmn[9]=has?c.y:0.f; vmn[10]=has?c.z:0.f; vmn[11]=has?c.w:0.f;
            vmn[12]=has?d.x:0.f; vmn[13]=has?d.y:0.f; vmn[14]=has?d.z:0.f; vmn[15]=has?d.w:0.f;
        }
        {
            const float4* s4a = (const float4*)(mxb + n * FF + kh * 8);
            const float4* s4b = (const float4*)(mxb + n * FF + 32 + kh * 8);
            float4 a = s4a[0], b = s4a[1], c = s4b[0], d = s4b[1];
            vmx[0]=has?a.x:0.f; vmx[1]=has?a.y:0.f; vmx[2]=has?a.z:0.f; vmx[3]=has?a.w:0.f;
            vmx[4]=has?b.x:0.f; vmx[5]=has?b.y:0.f; vmx[6]=has?b.z:0.f; vmx[7]=has?b.w:0.f;
            vmx[8]=has?c.x:0.f; vmx[9]=has?c.y:0.f; vmx[10]=has?c.z:0.f; vmx[11]=has?c.w:0.f;
            vmx[12]=has?d.x:0.f; vmx[13]=has?d.y:0.f; vmx[14]=has?d.z:0.f; vmx[15]=has?d.w:0.f;
        }
        const short8v* BH = (const short8v*)WFh;
        const short8v* BL = (const short8v*)WFl;
        f32x4 acc[4];
#pragma unroll
        for (int nt = 0; nt < 4; ++nt) { f32x4 z = {0.f,0.f,0.f,0.f}; acc[nt] = z; }
        short8v hv, lv;
#define DO_KC3(kc) { \
        _Pragma("unroll") for (int nt = 0; nt < 4; ++nt) { \
            acc[nt] = MFMA16(hv, BH[((kc) * 4 + nt) * 64 + lane], acc[nt]); \
            acc[nt] = MFMA16(lv, BH[((kc) * 4 + nt) * 64 + lane], acc[nt]); \
            acc[nt] = MFMA16(hv, BL[((kc) * 4 + nt) * 64 + lane], acc[nt]); } }
        pack8s(xr + kh * 8, hv, lv);        DO_KC3(0)
        pack8s(xr + 32 + kh * 8, hv, lv);   DO_KC3(1)
        pack8fs(vme + 0, hv, lv);           DO_KC3(2)
        pack8fs(vme + 8, hv, lv);           DO_KC3(3)
        pack8fs(vmn + 0, hv, lv);           DO_KC3(4)
        pack8fs(vmn + 8, hv, lv);           DO_KC3(5)
        pack8fs(vmx + 0, hv, lv);           DO_KC3(6)
        pack8fs(vmx + 8, hv, lv);           DO_KC3(7)
#pragma unroll
        for (int j = 0; j < 16; ++j) sc16[j] = vme[j] * av;
        pack8fs(sc16 + 0, hv, lv);          DO_KC3(8)
        pack8fs(sc16 + 8, hv, lv);          DO_KC3(9)
#pragma unroll
        for (int j = 0; j < 16; ++j) sc16[j] = vmn[j] * av;
        pack8fs(sc16 + 0, hv, lv);          DO_KC3(10)
        pack8fs(sc16 + 8, hv, lv);          DO_KC3(11)
#pragma unroll
        for (int j = 0; j < 16; ++j) sc16[j] = vmx[j] * av;
        pack8fs(sc16 + 0, hv, lv);          DO_KC3(12)
        pack8fs(sc16 + 8, hv, lv);          DO_KC3(13)
#undef DO_KC3
        float cfv[4];
#pragma unroll
        for (int nt = 0; nt < 4; ++nt) cfv[nt] = cfold_l[nt * 16 + m];
#pragma unroll
        for (int nt = 0; nt < 4; ++nt) {
            float ps = 0.f, pq = 0.f;
#pragma unroll
            for (int r = 0; r < 4; ++r) {
                float v = acc[nt][r] + cfv[nt];
                out_pre[(long)(g * 16 + kh * 4 + r) * FF + nt * 16 + m] = v;
                ps += v;
                pq += v * v;
            }
            atomicAdd(&sS[nt * 16 + m], ps);
            atomicAdd(&sQ[nt * 16 + m], pq);
        }
    }
    __syncthreads();
    if (t < FF) {
        atomicAdd(&bnsum[t], sS[t]);
        atomicAdd(&bnsum2[t], sQ[t]);
    }
}

// BN finalize + apply + ReLU in one kernel
__global__ void bn_apply2(const float* __restrict__ out_pre,
                          const float* __restrict__ bnsum, const float* __restrict__ bnsum2,
                          const float* __restrict__ gamma_l, const float* __restrict__ beta_l,
                          float* __restrict__ xout) {
    int f = threadIdx.x & 63;
    float mu = bnsum[f] / (float)NN;
    float var = bnsum2[f] / (float)NN - mu * mu;
    var = fmaxf(var, 0.f);
    float s = gamma_l[f] * rsqrtf(var + EPSBN);
    float o = beta_l[f] - mu * s;
    long i = (long)blockIdx.x * 256 + threadIdx.x;
    long stride = (long)gridDim.x * 256;   // multiple of 64 -> (j & 63) == f invariant
    for (long j = i; j < (long)NN * FF; j += stride) {
        xout[j] = fmaxf(fmaf(out_pre[j], s, o), 0.f);
    }
}

extern "C" void kernel_launch(void* const* d_in, const int* in_sizes, int n_in,
                              void* d_out, int out_size, void* d_ws, size_t ws_size,
                              hipStream_t stream) {
    const float* x0    = (const float*)d_in[0];
    const int*   ei    = (const int*)d_in[1];
    const float* attr  = (const float*)d_in[2];
    const float* We    = (const float*)d_in[3];
    const float* be    = (const float*)d_in[4];
    const float* Wpre  = (const float*)d_in[5];
    const float* bpre  = (const float*)d_in[6];
    const float* Wpost = (const float*)d_in[7];
    const float* bpost = (const float*)d_in[8];
    const float* Wlin  = (const float*)d_in[9];
    const float* blin  = (const float*)d_in[10];
    const float* gamma = (const float*)d_in[11];
    const float* beta  = (const float*)d_in[12];
    float* out = (float*)d_out;

    char* ws = (char*)d_ws;
    size_t off = 0;
    auto carve = [&](size_t bytes) -> void* {
        void* p = ws + off;
        off += (bytes + 255) & ~(size_t)255;
        return p;
    };
    const size_t NFb = (size_t)NN * FF * 4;
    float*    Weff   = (float*)carve(2 * EDIM * FF * 4);
    float*    beff   = (float*)carve(2 * FF * 4);
    float*    Wc     = (float*)carve(2 * 7 * FF * FF * 4);
    float*    cfold  = (float*)carve(2 * FF * 4);
    short*    WpreF  = (short*)carve(2 * 4096 * 2);
    short*    WeffF  = (short*)carve(2 * 2048 * 2);
    short*    WcFh   = (short*)carve(2 * 28672 * 2);
    short*    WcFl   = (short*)carve(2 * 28672 * 2);
    int*      srcp   = (int*)carve(NE * 4);
    int*      perm   = (int*)carve(NE * 4);
    int*      rowptr = (int*)carve((NN + 1) * 4);
    int*      rowcnt = (int*)carve(NN * 4);
    int*      fill   = (int*)carve(NN * 4);
    int*      bc     = (int*)carve(NN * 4);
    float*    amp    = (float*)carve(NN * 4);
    int*      part   = (int*)carve(NSCB * 4);
    short*    xpb    = (short*)carve((size_t)NN * FF * 2);
    float*    sumb   = (float*)carve(NFb);
    float*    mnb    = (float*)carve(NFb);
    float*    mxb    = (float*)carve(NFb);
    float*    xbuf   = (float*)carve(NFb);
    float*    bnsum  = (float*)carve(FF * 4);
    float*    bnsum2 = (float*)carve(FF * 4);
    float*    avglog = (float*)carve(4);
    // epc gets the remaining workspace: full-E chunk if it fits, else half
    size_t left = (ws_size > off) ? ws_size - off : 0;
    long ech = (left >= (size_t)NE * FF * 2 + 512) ? NE : NE / 2;
    short*    epc    = (short*)carve((size_t)ech * FF * 2);
    float*    out_pre = (float*)epc;   // epc dead after last agg chunk of each layer

    const int EB = (int)((NE + 255) / 256);

    // one-time build
    build_zero<<<196, 256, 0, stream>>>(rowcnt, fill, bc, avglog);
    hist_dst<<<EB, 256, 0, stream>>>(ei, rowcnt);
    scan_a<<<NSCB, SCB, 0, stream>>>(rowcnt, part);
    scan_b<<<1, 128, 0, stream>>>(part, rowptr);
    scan_c<<<NSCB, SCB, 0, stream>>>(rowcnt, part, rowptr);
    scatter2<<<EB, 256, 0, stream>>>(ei, rowptr, fill, srcp, perm);
    degbc2<<<196, 256, 0, stream>>>(rowcnt, bc);
    avglog_kernel<<<128, 256, 0, stream>>>(bc, avglog);
    amp_kernel<<<196, 256, 0, stream>>>(rowcnt, avglog, amp);
    fold_kernel<<<32, 256, 0, stream>>>(We, be, Wpre, bpre, Wpost, bpost, Wlin, blin,
                                        Weff, beff, Wc, cfold);
    fragify_all<<<34, 256, 0, stream>>>(Wpre, Weff, Wc, WpreF, WeffF, WcFh, WcFl);

    for (int l = 0; l < NLAYER; ++l) {
        const float* xin = (l == 0) ? x0 : xbuf;
        float* xout = (l == NLAYER - 1) ? out : xbuf;

        xp_mfma<<<(NGRP + 3) / 4, 256, 0, stream>>>(xin, WpreF + l * 4096, xpb, bnsum, bnsum2);
        for (long elo = 0; elo < NE; elo += ech) {
            ep_mfma<<<(int)(ech / 64), 256, 0, stream>>>(attr, perm, WeffF + l * 2048,
                                                         beff + l * FF, epc, elo);
            agg_merge<<<12500, 256, 0, stream>>>(rowptr, srcp, xpb, epc, elo, elo + ech,
                                                 (elo == 0) ? 1 : 0, sumb, mnb, mxb);
        }
        node_mfma<<<(NGRP + 3) / 4, 256, 0, stream>>>(xin, sumb, mnb, mxb, rowcnt, amp,
                                                      WcFh + l * 28672, WcFl + l * 28672,
                                                      cfold + l * FF,
                                                      out_pre, bnsum, bnsum2);
        bn_apply2<<<4096, 256, 0, stream>>>(out_pre, bnsum, bnsum2,
                                            gamma + l * FF, beta + l * FF, xout);
    }
}

// Round 7
// 375.793 us; speedup vs baseline: 3.5222x; 1.2972x over previous
//
#include <hip/hip_runtime.h>
#include <math.h>

static constexpr int NN = 50000;     // nodes
static constexpr long NE = 800000;   // edges
static constexpr int FF = 64;        // features
static constexpr int EDIM = 16;      // edge attr dim
static constexpr int NLAYER = 2;
static constexpr float EPSBN = 1e-5f;
static constexpr int NGRP = NN / 16;         // 3125 node groups of 16
static constexpr int SCB = 512;              // scan block size
static constexpr int NSCB = (NN + SCB - 1) / SCB;  // 98

typedef __attribute__((ext_vector_type(8))) short short8v;
typedef __attribute__((ext_vector_type(4))) float f32x4;

#define MFMA16(a, b, c) __builtin_amdgcn_mfma_f32_16x16x32_bf16(a, b, c, 0, 0, 0)

__device__ __forceinline__ short f2bf(float f) {
    unsigned u = __float_as_uint(f);
    unsigned r = u + 0x7FFFu + ((u >> 16) & 1u);   // RNE
    return (short)(r >> 16);
}
__device__ __forceinline__ float bf2f(unsigned short h) {
    return __uint_as_float(((unsigned)h) << 16);
}
__device__ __forceinline__ unsigned pk2(float lo, float hi) {
    return (unsigned)(unsigned short)f2bf(lo) | ((unsigned)(unsigned short)f2bf(hi) << 16);
}
__device__ __forceinline__ short8v pack8(const float* p) {
    const float4* q = (const float4*)p;
    float4 a = q[0], b = q[1];
    short8v v;
    v[0] = f2bf(a.x); v[1] = f2bf(a.y); v[2] = f2bf(a.z); v[3] = f2bf(a.w);
    v[4] = f2bf(b.x); v[5] = f2bf(b.y); v[6] = f2bf(b.z); v[7] = f2bf(b.w);
    return v;
}
// split pack: hi = bf16(v), lo = bf16(v - hi)
__device__ __forceinline__ void pack8s(const float* p, short8v& hi, short8v& lo) {
    const float4* q = (const float4*)p;
    float4 a = q[0], b = q[1];
    float v[8] = {a.x, a.y, a.z, a.w, b.x, b.y, b.z, b.w};
#pragma unroll
    for (int j = 0; j < 8; ++j) {
        short h = f2bf(v[j]);
        hi[j] = h;
        lo[j] = f2bf(v[j] - bf2f((unsigned short)h));
    }
}
__device__ __forceinline__ void pack8fs(const float* v, short8v& hi, short8v& lo) {
#pragma unroll
    for (int j = 0; j < 8; ++j) {
        short h = f2bf(v[j]);
        hi[j] = h;
        lo[j] = f2bf(v[j] - bf2f((unsigned short)h));
    }
}

// ---- fold weights (32 blocks: 2 layers x 16 slices) ----
__global__ void fold_kernel(const float* __restrict__ We, const float* __restrict__ be,
                            const float* __restrict__ Wpre, const float* __restrict__ bpre,
                            const float* __restrict__ Wpost, const float* __restrict__ bpost,
                            const float* __restrict__ Wlin, const float* __restrict__ blin,
                            float* __restrict__ Weff, float* __restrict__ beff,
                            float* __restrict__ Wc, float* __restrict__ cfold) {
    int l = blockIdx.x >> 4;
    int s = blockIdx.x & 15;
    int t = threadIdx.x;
    const float* We_l    = We    + l * EDIM * FF;
    const float* Wpre_e  = Wpre  + l * 2 * FF * FF + FF * FF;  // rows 64..127
    const float* Wpost_l = Wpost + l * 7 * FF * FF;
    const float* Wlin_l  = Wlin  + l * FF * FF;

    __shared__ float slin[FF * FF];
    __shared__ float spre[FF * FF];
    for (int i = t; i < FF * FF; i += blockDim.x) { slin[i] = Wlin_l[i]; spre[i] = Wpre_e[i]; }
    __syncthreads();

    for (int i = s * 256 + t; i < EDIM * FF; i += 16 * 256) {
        int j = i >> 6, f = i & 63;
        float a = 0.f;
        for (int k = 0; k < FF; ++k) a += We_l[j * FF + k] * spre[k * FF + f];
        Weff[l * EDIM * FF + i] = a;
    }
    for (int i = s * 256 + t; i < FF; i += 16 * 256) {
        float a = bpre[l * FF + i];
        for (int k = 0; k < FF; ++k) a += be[l * FF + k] * spre[k * FF + i];
        beff[l * FF + i] = a;
    }
    for (int i = s * 256 + t; i < 7 * FF * FF; i += 16 * 256) {
        int r = i >> 6, f = i & 63;
        float a = 0.f;
        for (int k = 0; k < FF; ++k) a += Wpost_l[r * FF + k] * slin[k * FF + f];
        Wc[l * 7 * FF * FF + i] = a;
    }
    for (int i = s * 256 + t; i < FF; i += 16 * 256) {
        float a = blin[l * FF + i];
        for (int k = 0; k < FF; ++k) a += bpost[l * FF + k] * slin[k * FF + i];
        cfold[l * FF + i] = a;
    }
}

// ---- all weight fragments in one launch. 34 blocks: 2 layers x (2 Wpre + 1 Weff + 14 Wc)
__global__ void fragify_all(const float* __restrict__ Wpre, const float* __restrict__ Weff,
                            const float* __restrict__ Wc,
                            short* __restrict__ WpreF, short* __restrict__ WeffF,
                            short* __restrict__ WcFh, short* __restrict__ WcFl) {
    int b = blockIdx.x;          // 0..33
    int l = b / 17, r = b % 17;
    int t = threadIdx.x;
    const float* src; short* dh; short* dl = nullptr; int kc, Kreal;
    if (r < 2)      { src = Wpre + (size_t)l * 2 * FF * FF; dh = WpreF + l * 4096;  kc = r;     Kreal = 64; }
    else if (r < 3) { src = Weff + (size_t)l * EDIM * FF;   dh = WeffF + l * 2048;  kc = 0;     Kreal = 16; }
    else            { src = Wc   + (size_t)l * 7 * FF * FF; dh = WcFh + l * 28672;
                      dl = WcFl + l * 28672;                                        kc = r - 3; Kreal = 448; }
    int idx = kc * 256 + t;
    int lane = idx & 63, nt = (idx >> 6) & 3;
    int m = lane & 15, kh = lane >> 4;
    short8v hv, lv;
#pragma unroll
    for (int j = 0; j < 8; ++j) {
        int k = kc * 32 + kh * 8 + j;
        float val = (k < Kreal) ? src[k * FF + nt * 16 + m] : 0.f;
        short h = f2bf(val);
        hv[j] = h;
        lv[j] = f2bf(val - bf2f((unsigned short)h));
    }
    ((short8v*)dh)[idx] = hv;
    if (dl) ((short8v*)dl)[idx] = lv;
}

// ================= CSR build phase ==========

__global__ void build_zero(int* __restrict__ rowcnt, int* __restrict__ fill,
                           int* __restrict__ bc, float* __restrict__ avglog) {
    long i = (long)blockIdx.x * 256 + threadIdx.x;
    long stride = (long)gridDim.x * 256;
    for (long j = i; j < NN; j += stride) { rowcnt[j] = 0; fill[j] = 0; bc[j] = 0; }
    if (i == 0) avglog[0] = 0.f;
}

__global__ void hist_dst(const int* __restrict__ ei, int* __restrict__ rowcnt) {
    long e = (long)blockIdx.x * 256 + threadIdx.x;
    if (e < NE) atomicAdd(&rowcnt[ei[NE + e]], 1);
}

// ---- hierarchical exclusive scan: rowcnt[NN] -> rowptr[NN+1] ----
__global__ void scan_a(const int* __restrict__ rowcnt, int* __restrict__ part) {
    __shared__ int red[SCB];
    int t = threadIdx.x;
    int i = blockIdx.x * SCB + t;
    red[t] = (i < NN) ? rowcnt[i] : 0;
    __syncthreads();
    for (int o = SCB / 2; o > 0; o >>= 1) {
        if (t < o) red[t] += red[t + o];
        __syncthreads();
    }
    if (t == 0) part[blockIdx.x] = red[0];
}

__global__ void scan_b(int* __restrict__ part, int* __restrict__ rowptr) {
    __shared__ int s[128];
    int t = threadIdx.x;
    int v = (t < NSCB) ? part[t] : 0;
    s[t] = v;
    __syncthreads();
    for (int o = 1; o < 128; o <<= 1) {
        int u = (t >= o) ? s[t - o] : 0;
        __syncthreads();
        s[t] += u;
        __syncthreads();
    }
    if (t < NSCB) part[t] = s[t] - v;          // exclusive block offset
    if (t == 127) rowptr[NN] = s[127];         // total
}

__global__ void scan_c(const int* __restrict__ rowcnt, const int* __restrict__ part,
                       int* __restrict__ rowptr) {
    __shared__ int s[SCB];
    int t = threadIdx.x;
    int i = blockIdx.x * SCB + t;
    int v = (i < NN) ? rowcnt[i] : 0;
    s[t] = v;
    __syncthreads();
    for (int o = 1; o < SCB; o <<= 1) {
        int u = (t >= o) ? s[t - o] : 0;
        __syncthreads();
        s[t] += u;
        __syncthreads();
    }
    if (i < NN) rowptr[i] = part[blockIdx.x] + s[t] - v;
}

// scatter edges into CSR order; materialize bf16 attr in CSR order (gather paid ONCE)
__global__ void scatter2(const int* __restrict__ ei, const float* __restrict__ attr,
                         const int* __restrict__ rowptr, int* __restrict__ fill,
                         int* __restrict__ srcp, short* __restrict__ attrb) {
    long e = (long)blockIdx.x * 256 + threadIdx.x;
    if (e >= NE) return;
    int d = ei[NE + e];
    int p = rowptr[d] + atomicAdd(&fill[d], 1);
    srcp[p] = ei[e];
    const float4* a4 = (const float4*)(attr + e * EDIM);
    float4 A = a4[0], B = a4[1], C = a4[2], D = a4[3];
    uint4 w0, w1;
    w0.x = pk2(A.x, A.y); w0.y = pk2(A.z, A.w); w0.z = pk2(B.x, B.y); w0.w = pk2(B.z, B.w);
    w1.x = pk2(C.x, C.y); w1.y = pk2(C.z, C.w); w1.z = pk2(D.x, D.y); w1.w = pk2(D.z, D.w);
    uint4* dst = (uint4*)(attrb + (long)p * EDIM);
    dst[0] = w0; dst[1] = w1;
}

// LDS-privatized degree histogram
__global__ void degbc2(const int* __restrict__ rowcnt, int* __restrict__ bc) {
    __shared__ int h[256];
    int t = threadIdx.x;
    h[t] = 0;
    __syncthreads();
    for (long n = (long)blockIdx.x * 256 + t; n < NN; n += (long)gridDim.x * 256) {
        int d = rowcnt[n];
        if (d < 256) {
            atomicAdd(&h[d], 1);
        } else {
            if (d >= NN) d = NN - 1;
            atomicAdd(&bc[d], 1);
        }
    }
    __syncthreads();
    int v = h[t];
    if (v) atomicAdd(&bc[t], v);
}

__global__ void avglog_kernel(const int* __restrict__ bc, float* __restrict__ total) {
    float s = 0.f;
    for (long i = (long)blockIdx.x * 256 + threadIdx.x; i < NN; i += (long)gridDim.x * 256)
        s += logf((float)bc[i] + 1.f);
    for (int o = 32; o; o >>= 1) s += __shfl_down(s, o, 64);
    __shared__ float wsum[4];
    int lane = threadIdx.x & 63, wid = threadIdx.x >> 6;
    if (lane == 0) wsum[wid] = s;
    __syncthreads();
    if (threadIdx.x == 0) atomicAdd(total, wsum[0] + wsum[1] + wsum[2] + wsum[3]);
}

__global__ void amp_kernel(const int* __restrict__ cnt, const float* __restrict__ total,
                           float* __restrict__ amp) {
    long n = (long)blockIdx.x * 256 + threadIdx.x;
    if (n < NN) {
        float avg = total[0] / (float)NN;
        float sc = fmaxf((float)cnt[n], 1.f);
        amp[n] = logf(sc + 1.f) / avg;
    }
}

// ================= per-layer kernels ==========

// xp = x @ Wpre[0:64] -> bf16, via MFMA. wave per 16-node group. block 0 zeroes BN sums.
__global__ __launch_bounds__(256) void xp_mfma(const float* __restrict__ xin,
                                               const short* __restrict__ WF,
                                               short* __restrict__ xpb,
                                               float* __restrict__ bnsum,
                                               float* __restrict__ bnsum2) {
    int t = threadIdx.x;
    if (blockIdx.x == 0 && t < FF) { bnsum[t] = 0.f; bnsum2[t] = 0.f; }
    int g = blockIdx.x * 4 + (t >> 6);
    if (g >= NGRP) return;
    int lane = t & 63, m = lane & 15, kh = lane >> 4;
    const float* xr = xin + (long)(g * 16 + m) * FF;
    short8v a0 = pack8(xr + kh * 8);
    short8v a1 = pack8(xr + 32 + kh * 8);
    const short8v* BF = (const short8v*)WF;
    f32x4 acc[4];
#pragma unroll
    for (int nt = 0; nt < 4; ++nt) {
        f32x4 z = {0.f, 0.f, 0.f, 0.f};
        z = MFMA16(a0, BF[(0 * 4 + nt) * 64 + lane], z);
        z = MFMA16(a1, BF[(1 * 4 + nt) * 64 + lane], z);
        acc[nt] = z;
    }
#pragma unroll
    for (int nt = 0; nt < 4; ++nt)
#pragma unroll
        for (int r = 0; r < 4; ++r) {
            long node = g * 16 + kh * 4 + r;
            xpb[node * FF + nt * 16 + m] = f2bf(acc[nt][r]);
        }
}

// ep = attrb @ Weff + beff -> bf16 (attrb already CSR-ordered bf16). wave per 16 edges.
__global__ __launch_bounds__(256) void ep_mfma(const short* __restrict__ attrb,
                                               const short* __restrict__ WF,
                                               const float* __restrict__ beff_l,
                                               short* __restrict__ epc, long elo) {
    int t = threadIdx.x;
    int g = blockIdx.x * 4 + (t >> 6);
    int lane = t & 63, m = lane & 15, kh = lane >> 4;
    long p0 = elo + (long)g * 16;
    short8v a;
    if (kh < 2) {
        a = *(const short8v*)(attrb + (p0 + m) * EDIM + kh * 8);
    } else {
#pragma unroll
        for (int j = 0; j < 8; ++j) a[j] = 0;
    }
    const short8v* BF = (const short8v*)WF;
    float bfv[4];
#pragma unroll
    for (int nt = 0; nt < 4; ++nt) bfv[nt] = beff_l[nt * 16 + m];
    f32x4 acc[4];
#pragma unroll
    for (int nt = 0; nt < 4; ++nt) {
        f32x4 z = {0.f, 0.f, 0.f, 0.f};
        acc[nt] = MFMA16(a, BF[nt * 64 + lane], z);
    }
#pragma unroll
    for (int nt = 0; nt < 4; ++nt)
#pragma unroll
        for (int r = 0; r < 4; ++r) {
            long rel = (long)g * 16 + kh * 4 + r;
            epc[rel * FF + nt * 16 + m] = f2bf(acc[nt][r] + bfv[nt]);
        }
}

// CSR aggregation over edge chunk [elo,ehi): h = xp[src] + ep.
// srcp pre-loaded lane-parallel + shfl broadcast (no uniform-load chain);
// 4 independent gathers per iteration (static regs) -> latency hidden.
__global__ __launch_bounds__(256) void agg_merge(
    const int* __restrict__ rowptr, const int* __restrict__ srcp,
    const short* __restrict__ xpb, const short* __restrict__ epc,
    long elo, long ehi, int first,
    float* __restrict__ sumb, float* __restrict__ mnb, float* __restrict__ mxb) {
    int t = threadIdx.x;
    int n = blockIdx.x * 4 + (t >> 6);
    if (n >= NN) return;
    int lane = t & 63;
    long r0 = rowptr[n], r1 = rowptr[n + 1];
    long lo = r0 > elo ? r0 : elo;
    long hi = r1 < ehi ? r1 : ehi;
    const float INF = __builtin_huge_valf();
    float sm = 0.f, mn = INF, mx = -INF;
    if (!first && lo >= hi) return;
    const unsigned short* xu = (const unsigned short*)xpb;
    const unsigned short* eu = (const unsigned short*)epc;
    for (long base = lo; base < hi; base += 64) {
        int cnt = (int)(((hi - base) < 64) ? (hi - base) : 64);
        int sv = srcp[base + (lane < cnt ? lane : cnt - 1)];
        long eb = base - elo;
        int j = 0;
        for (; j + 4 <= cnt; j += 4) {
            int s0 = __shfl(sv, j + 0), s1 = __shfl(sv, j + 1);
            int s2 = __shfl(sv, j + 2), s3 = __shfl(sv, j + 3);
            float x0 = bf2f(xu[(long)s0 * FF + lane]);
            float x1 = bf2f(xu[(long)s1 * FF + lane]);
            float x2 = bf2f(xu[(long)s2 * FF + lane]);
            float x3 = bf2f(xu[(long)s3 * FF + lane]);
            float e0 = bf2f(eu[(eb + j + 0) * FF + lane]);
            float e1 = bf2f(eu[(eb + j + 1) * FF + lane]);
            float e2 = bf2f(eu[(eb + j + 2) * FF + lane]);
            float e3 = bf2f(eu[(eb + j + 3) * FF + lane]);
            float h0 = x0 + e0, h1 = x1 + e1, h2 = x2 + e2, h3 = x3 + e3;
            sm += (h0 + h1) + (h2 + h3);
            mn = fminf(mn, fminf(fminf(h0, h1), fminf(h2, h3)));
            mx = fmaxf(mx, fmaxf(fmaxf(h0, h1), fmaxf(h2, h3)));
        }
        for (; j < cnt; ++j) {
            int s0 = __shfl(sv, j);
            float h = bf2f(xu[(long)s0 * FF + lane]) + bf2f(eu[(eb + j) * FF + lane]);
            sm += h;
            mn = fminf(mn, h);
            mx = fmaxf(mx, h);
        }
    }
    long o = (long)n * FF + lane;
    if (first) {
        sumb[o] = sm; mnb[o] = mn; mxb[o] = mx;
    } else {
        sumb[o] += sm;
        mnb[o] = fminf(mnb[o], mn);
        mxb[o] = fmaxf(mxb[o], mx);
    }
}

// node GEMM via split-bf16 MFMA (3 MFMA per frag: ah*bh + al*bh + ah*bl).
__global__ __launch_bounds__(256) void node_mfma(
    const float* __restrict__ xin, const float* __restrict__ sumb,
    const float* __restrict__ mnb, const float* __restrict__ mxb,
    const int* __restrict__ rowcnt, const float* __restrict__ amp,
    const short* __restrict__ WFh, const short* __restrict__ WFl,
    const float* __restrict__ cfold_l,
    float* __restrict__ out_pre, float* __restrict__ bnsum, float* __restrict__ bnsum2) {
    __shared__ float sS[FF], sQ[FF];
    int t = threadIdx.x;
    if (t < FF) { sS[t] = 0.f; sQ[t] = 0.f; }
    __syncthreads();
    int g = blockIdx.x * 4 + (t >> 6);
    bool act = (g < NGRP);
    int lane = t & 63, m = lane & 15, kh = lane >> 4;
    if (act) {
        long n = g * 16 + m;
        int deg = rowcnt[n];
        float inv = 1.f / fmaxf((float)deg, 1.f);
        bool has = (deg > 0);
        float av = amp[n];
        const float* xr = xin + n * FF;
        float vme[16], vmn[16], vmx[16], sc16[16];
        {
            const float4* s4a = (const float4*)(sumb + n * FF + kh * 8);
            const float4* s4b = (const float4*)(sumb + n * FF + 32 + kh * 8);
            float4 a = s4a[0], b = s4a[1], c = s4b[0], d = s4b[1];
            vme[0]=a.x*inv; vme[1]=a.y*inv; vme[2]=a.z*inv; vme[3]=a.w*inv;
            vme[4]=b.x*inv; vme[5]=b.y*inv; vme[6]=b.z*inv; vme[7]=b.w*inv;
            vme[8]=c.x*inv; vme[9]=c.y*inv; vme[10]=c.z*inv; vme[11]=c.w*inv;
            vme[12]=d.x*inv; vme[13]=d.y*inv; vme[14]=d.z*inv; vme[15]=d.w*inv;
        }
        {
            const float4* s4a = (const float4*)(mnb + n * FF + kh * 8);
            const float4* s4b = (const float4*)(mnb + n * FF + 32 + kh * 8);
            float4 a = s4a[0], b = s4a[1], c = s4b[0], d = s4b[1];
            vmn[0]=has?a.x:0.f; vmn[1]=has?a.y:0.f; vmn[2]=has?a.z:0.f; vmn[3]=has?a.w:0.f;
            vmn[4]=has?b.x:0.f; vmn[5]=has?b.y:0.f; vmn[6]=has?b.z:0.f; vmn[7]=has?b.w:0.f;
            vmn[8]=has?c.x:0.f; vmn[9]=has?c.y:0.f; vmn[10]=has?c.z:0.f; vmn[11]=has?c.w:0.f;
            vmn[12]=has?d.x:0.f; vmn[13]=has?d.y:0.f; vmn[14]=has?d.z:0.f; vmn[15]=has?d.w:0.f;
        }
        {
            const float4* s4a = (const float4*)(mxb + n * FF + kh * 8);
            const float4* s4b = (const float4*)(mxb + n * FF + 32 + kh * 8);
            float4 a = s4a[0], b = s4a[1], c = s4b[0], d = s4b[1];
            vmx[0]=has?a.x:0.f; vmx[1]=has?a.y:0.f; vmx[2]=has?a.z:0.f; vmx[3]=has?a.w:0.f;
            vmx[4]=has?b.x:0.f; vmx[5]=has?b.y:0.f; vmx[6]=has?b.z:0.f; vmx[7]=has?b.w:0.f;
            vmx[8]=has?c.x:0.f; vmx[9]=has?c.y:0.f; vmx[10]=has?c.z:0.f; vmx[11]=has?c.w:0.f;
            vmx[12]=has?d.x:0.f; vmx[13]=has?d.y:0.f; vmx[14]=has?d.z:0.f; vmx[15]=has?d.w:0.f;
        }
        const short8v* BH = (const short8v*)WFh;
        const short8v* BL = (const short8v*)WFl;
        f32x4 acc[4];
#pragma unroll
        for (int nt = 0; nt < 4; ++nt) { f32x4 z = {0.f,0.f,0.f,0.f}; acc[nt] = z; }
        short8v hv, lv;
#define DO_KC3(kc) { \
        _Pragma("unroll") for (int nt = 0; nt < 4; ++nt) { \
            acc[nt] = MFMA16(hv, BH[((kc) * 4 + nt) * 64 + lane], acc[nt]); \
            acc[nt] = MFMA16(lv, BH[((kc) * 4 + nt) * 64 + lane], acc[nt]); \
            acc[nt] = MFMA16(hv, BL[((kc) * 4 + nt) * 64 + lane], acc[nt]); } }
        pack8s(xr + kh * 8, hv, lv);        DO_KC3(0)
        pack8s(xr + 32 + kh * 8, hv, lv);   DO_KC3(1)
        pack8fs(vme + 0, hv, lv);           DO_KC3(2)
        pack8fs(vme + 8, hv, lv);           DO_KC3(3)
        pack8fs(vmn + 0, hv, lv);           DO_KC3(4)
        pack8fs(vmn + 8, hv, lv);           DO_KC3(5)
        pack8fs(vmx + 0, hv, lv);           DO_KC3(6)
        pack8fs(vmx + 8, hv, lv);           DO_KC3(7)
#pragma unroll
        for (int j = 0; j < 16; ++j) sc16[j] = vme[j] * av;
        pack8fs(sc16 + 0, hv, lv);          DO_KC3(8)
        pack8fs(sc16 + 8, hv, lv);          DO_KC3(9)
#pragma unroll
        for (int j = 0; j < 16; ++j) sc16[j] = vmn[j] * av;
        pack8fs(sc16 + 0, hv, lv);          DO_KC3(10)
        pack8fs(sc16 + 8, hv, lv);          DO_KC3(11)
#pragma unroll
        for (int j = 0; j < 16; ++j) sc16[j] = vmx[j] * av;
        pack8fs(sc16 + 0, hv, lv);          DO_KC3(12)
        pack8fs(sc16 + 8, hv, lv);          DO_KC3(13)
#undef DO_KC3
        float cfv[4];
#pragma unroll
        for (int nt = 0; nt < 4; ++nt) cfv[nt] = cfold_l[nt * 16 + m];
#pragma unroll
        for (int nt = 0; nt < 4; ++nt) {
            float ps = 0.f, pq = 0.f;
#pragma unroll
            for (int r = 0; r < 4; ++r) {
                float v = acc[nt][r] + cfv[nt];
                out_pre[(long)(g * 16 + kh * 4 + r) * FF + nt * 16 + m] = v;
                ps += v;
                pq += v * v;
            }
            atomicAdd(&sS[nt * 16 + m], ps);
            atomicAdd(&sQ[nt * 16 + m], pq);
        }
    }
    __syncthreads();
    if (t < FF) {
        atomicAdd(&bnsum[t], sS[t]);
        atomicAdd(&bnsum2[t], sQ[t]);
    }
}

// BN finalize + apply + ReLU in one kernel
__global__ void bn_apply2(const float* __restrict__ out_pre,
                          const float* __restrict__ bnsum, const float* __restrict__ bnsum2,
                          const float* __restrict__ gamma_l, const float* __restrict__ beta_l,
                          float* __restrict__ xout) {
    int f = threadIdx.x & 63;
    float mu = bnsum[f] / (float)NN;
    float var = bnsum2[f] / (float)NN - mu * mu;
    var = fmaxf(var, 0.f);
    float s = gamma_l[f] * rsqrtf(var + EPSBN);
    float o = beta_l[f] - mu * s;
    long i = (long)blockIdx.x * 256 + threadIdx.x;
    long stride = (long)gridDim.x * 256;   // multiple of 64 -> (j & 63) == f invariant
    for (long j = i; j < (long)NN * FF; j += stride) {
        xout[j] = fmaxf(fmaf(out_pre[j], s, o), 0.f);
    }
}

extern "C" void kernel_launch(void* const* d_in, const int* in_sizes, int n_in,
                              void* d_out, int out_size, void* d_ws, size_t ws_size,
                              hipStream_t stream) {
    const float* x0    = (const float*)d_in[0];
    const int*   ei    = (const int*)d_in[1];
    const float* attr  = (const float*)d_in[2];
    const float* We    = (const float*)d_in[3];
    const float* be    = (const float*)d_in[4];
    const float* Wpre  = (const float*)d_in[5];
    const float* bpre  = (const float*)d_in[6];
    const float* Wpost = (const float*)d_in[7];
    const float* bpost = (const float*)d_in[8];
    const float* Wlin  = (const float*)d_in[9];
    const float* blin  = (const float*)d_in[10];
    const float* gamma = (const float*)d_in[11];
    const float* beta  = (const float*)d_in[12];
    float* out = (float*)d_out;

    char* ws = (char*)d_ws;
    size_t off = 0;
    auto carve = [&](size_t bytes) -> void* {
        void* p = ws + off;
        off += (bytes + 255) & ~(size_t)255;
        return p;
    };
    const size_t NFb = (size_t)NN * FF * 4;
    float*    Weff   = (float*)carve(2 * EDIM * FF * 4);
    float*    beff   = (float*)carve(2 * FF * 4);
    float*    Wc     = (float*)carve(2 * 7 * FF * FF * 4);
    float*    cfold  = (float*)carve(2 * FF * 4);
    short*    WpreF  = (short*)carve(2 * 4096 * 2);
    short*    WeffF  = (short*)carve(2 * 2048 * 2);
    short*    WcFh   = (short*)carve(2 * 28672 * 2);
    short*    WcFl   = (short*)carve(2 * 28672 * 2);
    int*      srcp   = (int*)carve(NE * 4);
    short*    attrb  = (short*)carve((size_t)NE * EDIM * 2);   // 25.6 MB, CSR-ordered bf16 attr
    int*      rowptr = (int*)carve((NN + 1) * 4);
    int*      rowcnt = (int*)carve(NN * 4);
    int*      fill   = (int*)carve(NN * 4);
    int*      bc     = (int*)carve(NN * 4);
    float*    amp    = (float*)carve(NN * 4);
    int*      part   = (int*)carve(NSCB * 4);
    short*    xpb    = (short*)carve((size_t)NN * FF * 2);
    float*    sumb   = (float*)carve(NFb);
    float*    mnb    = (float*)carve(NFb);
    float*    mxb    = (float*)carve(NFb);
    float*    xbuf   = (float*)carve(NFb);
    float*    bnsum  = (float*)carve(FF * 4);
    float*    bnsum2 = (float*)carve(FF * 4);
    float*    avglog = (float*)carve(4);
    // epc gets the remaining workspace: full-E chunk if it fits, else half
    size_t left = (ws_size > off) ? ws_size - off : 0;
    long ech = (left >= (size_t)NE * FF * 2 + 512) ? NE : NE / 2;
    short*    epc    = (short*)carve((size_t)ech * FF * 2);
    float*    out_pre = (float*)epc;   // epc dead after last agg chunk of each layer

    const int EB = (int)((NE + 255) / 256);

    // one-time build
    build_zero<<<196, 256, 0, stream>>>(rowcnt, fill, bc, avglog);
    hist_dst<<<EB, 256, 0, stream>>>(ei, rowcnt);
    scan_a<<<NSCB, SCB, 0, stream>>>(rowcnt, part);
    scan_b<<<1, 128, 0, stream>>>(part, rowptr);
    scan_c<<<NSCB, SCB, 0, stream>>>(rowcnt, part, rowptr);
    scatter2<<<EB, 256, 0, stream>>>(ei, attr, rowptr, fill, srcp, attrb);
    degbc2<<<196, 256, 0, stream>>>(rowcnt, bc);
    avglog_kernel<<<128, 256, 0, stream>>>(bc, avglog);
    amp_kernel<<<196, 256, 0, stream>>>(rowcnt, avglog, amp);
    fold_kernel<<<32, 256, 0, stream>>>(We, be, Wpre, bpre, Wpost, bpost, Wlin, blin,
                                        Weff, beff, Wc, cfold);
    fragify_all<<<34, 256, 0, stream>>>(Wpre, Weff, Wc, WpreF, WeffF, WcFh, WcFl);

    for (int l = 0; l < NLAYER; ++l) {
        const float* xin = (l == 0) ? x0 : xbuf;
        float* xout = (l == NLAYER - 1) ? out : xbuf;

        xp_mfma<<<(NGRP + 3) / 4, 256, 0, stream>>>(xin, WpreF + l * 4096, xpb, bnsum, bnsum2);
        for (long elo = 0; elo < NE; elo += ech) {
            ep_mfma<<<(int)(ech / 64), 256, 0, stream>>>(attrb, WeffF + l * 2048,
                                                         beff + l * FF, epc, elo);
            agg_merge<<<12500, 256, 0, stream>>>(rowptr, srcp, xpb, epc, elo, elo + ech,
                                                 (elo == 0) ? 1 : 0, sumb, mnb, mxb);
        }
        node_mfma<<<(NGRP + 3) / 4, 256, 0, stream>>>(xin, sumb, mnb, mxb, rowcnt, amp,
                                                      WcFh + l * 28672, WcFl + l * 28672,
                                                      cfold + l * FF,
                                                      out_pre, bnsum, bnsum2);
        bn_apply2<<<4096, 256, 0, stream>>>(out_pre, bnsum, bnsum2,
                                            gamma + l * FF, beta + l * FF, xout);
    }
}